// Round 1
// baseline (1333.531 us; speedup 1.0000x reference)
//
#include <hip/hip_runtime.h>
#include <math.h>

#define BB 8
#define AA 1024
#define NN 64
#define FF 128
#define NG 25

#define WIDTH 0.2083333333f     /* 5/24 */
#define COEF  (-0.5f/(WIDTH*WIDTH))
#define PI_F  3.14159265358979f

__device__ __forceinline__ float sspf(float x){
    // shifted softplus: log(1+e^x) - log(2), stable
    return fmaxf(x, 0.f) + log1pf(expf(-fabsf(x))) - 0.69314718056f;
}

// ---------------- geometry precompute: masked r and C*mask ----------------
__global__ void k_pre(const float* __restrict__ pos, const float* __restrict__ cell,
                      const float* __restrict__ coff, const int* __restrict__ nbr,
                      const float* __restrict__ mask,
                      float* __restrict__ rbuf, float* __restrict__ cbuf){
    int flat = blockIdx.x*256 + threadIdx.x;         // < B*A*N
    int b = flat >> 16;
    int a = (flat >> 6) & (AA-1);
    int j = nbr[flat];
    const float* pi = pos + (b*AA + a)*3;
    const float* pj = pos + (b*AA + j)*3;
    const float* co = coff + (size_t)flat*3;
    const float* cl = cell + b*9;
    float ox = co[0]*cl[0] + co[1]*cl[3] + co[2]*cl[6];
    float oy = co[0]*cl[1] + co[1]*cl[4] + co[2]*cl[7];
    float oz = co[0]*cl[2] + co[1]*cl[5] + co[2]*cl[8];
    float vx = pj[0]-pi[0]+ox, vy = pj[1]-pi[1]+oy, vz = pj[2]-pi[2]+oz;
    float d2 = vx*vx + vy*vy + vz*vz;
    float m  = mask[flat];
    float r  = sqrtf(m > 0.f ? d2 : 1.0f) * m;
    float C  = 0.5f*(cosf(r*(PI_F/5.0f)) + 1.0f) * (r < 5.0f ? 1.f : 0.f);
    rbuf[flat] = r;
    cbuf[flat] = C*m;
}

// ---------------- x0 = embed[atomic_numbers] ----------------
__global__ void k_init(const int* __restrict__ z, const float* __restrict__ emb,
                       float* __restrict__ x){
    int idx = blockIdx.x*256 + threadIdx.x;          // < B*A*F
    int atom = idx >> 7;
    int f = idx & (FF-1);
    x[idx] = emb[z[atom]*FF + f];
}

// ---------------- y = x @ in2f_w (no bias); 8 rows per block ----------------
__global__ __launch_bounds__(256) void k_in2f(const float* __restrict__ x,
                                              const float* __restrict__ w,
                                              float* __restrict__ y){
    __shared__ float sx[8][FF];
    int tid = threadIdx.x;
    int rb = blockIdx.x*8;
    for(int i = tid; i < 8*FF; i += 256) sx[i>>7][i&(FF-1)] = x[rb*FF + i];
    __syncthreads();
    int f = tid & (FF-1), rh = tid >> 7;
    float acc[4] = {0.f,0.f,0.f,0.f};
    for(int kc = 0; kc < 32; kc++){
        float w0 = w[(4*kc+0)*FF+f];
        float w1 = w[(4*kc+1)*FF+f];
        float w2 = w[(4*kc+2)*FF+f];
        float w3 = w[(4*kc+3)*FF+f];
        #pragma unroll
        for(int rr = 0; rr < 4; rr++){
            float4 xv = *(const float4*)&sx[rh+2*rr][4*kc];
            acc[rr] = fmaf(xv.x,w0,fmaf(xv.y,w1,fmaf(xv.z,w2,fmaf(xv.w,w3,acc[rr]))));
        }
    }
    #pragma unroll
    for(int rr = 0; rr < 4; rr++) y[(rb+rh+2*rr)*FF + f] = acc[rr];
}

// ------- fused: gaussians -> Dense+ssp -> Dense -> *C -> gather-mul-reduce -------
// one block per atom; 256 threads
__global__ __launch_bounds__(256) void k_conv(const float* __restrict__ rbuf,
                                              const float* __restrict__ cbuf,
                                              const int* __restrict__ nbr,
                                              const float* __restrict__ y,
                                              const float* __restrict__ fw1,
                                              const float* __restrict__ fb1,
                                              const float* __restrict__ fw2,
                                              const float* __restrict__ fb2,
                                              float* __restrict__ agg){
    __shared__ float s_fij[NN][28];
    __shared__ float s_H[NN][FF];
    __shared__ float s_r[NN];
    __shared__ float s_ce[NN];
    __shared__ int   s_j[NN];
    __shared__ float s_red[3*FF];

    int tid = threadIdx.x;
    int row = blockIdx.x;              // b*A + a
    int b = row >> 10;

    if(tid < NN){
        s_r[tid]  = rbuf[row*NN + tid];
        s_ce[tid] = cbuf[row*NN + tid];
        s_j[tid]  = nbr[row*NN + tid];
    }
    __syncthreads();

    // gaussian smearing into LDS (padded to 28 for float4 reads)
    for(int idx = tid; idx < NN*28; idx += 256){
        int n = idx/28, g = idx - 28*n;
        float d = s_r[n] - g*WIDTH;
        s_fij[n][g] = (g < NG) ? expf(COEF*d*d) : 0.f;
    }

    // H = ssp(f_ij @ fw1 + fb1): f per lane, fw1 column in regs
    int f = tid & (FF-1), half = tid >> 7;
    float w1r[28];
    #pragma unroll
    for(int g = 0; g < NG; g++) w1r[g] = fw1[g*FF + f];
    w1r[25] = w1r[26] = w1r[27] = 0.f;
    float b1 = fb1[f];
    __syncthreads();

    #pragma unroll 4
    for(int rep = 0; rep < 32; rep++){
        int n = 2*rep + half;
        float acc = b1;
        #pragma unroll
        for(int gc = 0; gc < 7; gc++){
            float4 fv = *(const float4*)&s_fij[n][4*gc];
            acc = fmaf(fv.x, w1r[4*gc+0], acc);
            acc = fmaf(fv.y, w1r[4*gc+1], acc);
            acc = fmaf(fv.z, w1r[4*gc+2], acc);
            acc = fmaf(fv.w, w1r[4*gc+3], acc);
        }
        s_H[n][f] = sspf(acc);
    }
    __syncthreads();

    // W = H @ fw2 + fb2 ; 2 features per thread, 16 neighbors per thread
    int f0 = 2*(tid & 63), q = tid >> 6;
    float acc0[16], acc1[16];
    {
        float2 b2 = *(const float2*)&fb2[f0];
        #pragma unroll
        for(int rep = 0; rep < 16; rep++){ acc0[rep] = b2.x; acc1[rep] = b2.y; }
    }
    for(int kc = 0; kc < 32; kc++){
        float2 wa = *(const float2*)&fw2[(4*kc+0)*FF + f0];
        float2 wb = *(const float2*)&fw2[(4*kc+1)*FF + f0];
        float2 wc = *(const float2*)&fw2[(4*kc+2)*FF + f0];
        float2 wd = *(const float2*)&fw2[(4*kc+3)*FF + f0];
        #pragma unroll
        for(int rep = 0; rep < 16; rep++){
            int n = 4*rep + q;
            float4 hv = *(const float4*)&s_H[n][4*kc];
            acc0[rep] = fmaf(hv.x,wa.x,fmaf(hv.y,wb.x,fmaf(hv.z,wc.x,fmaf(hv.w,wd.x,acc0[rep]))));
            acc1[rep] = fmaf(hv.x,wa.y,fmaf(hv.y,wb.y,fmaf(hv.z,wc.y,fmaf(hv.w,wd.y,acc1[rep]))));
        }
    }

    // aggregate: sum_n (W*C*mask) * y[neighbor]
    float ag0 = 0.f, ag1 = 0.f;
    #pragma unroll
    for(int rep = 0; rep < 16; rep++){
        int n = 4*rep + q;
        float ce = s_ce[n];
        float2 yv = *(const float2*)&y[(size_t)(b*AA + s_j[n])*FF + f0];
        ag0 = fmaf(acc0[rep]*ce, yv.x, ag0);
        ag1 = fmaf(acc1[rep]*ce, yv.y, ag1);
    }
    if(q > 0){
        s_red[(q-1)*FF + f0]   = ag0;
        s_red[(q-1)*FF + f0+1] = ag1;
    }
    __syncthreads();
    if(q == 0){
        ag0 += s_red[f0]     + s_red[FF+f0]     + s_red[2*FF+f0];
        ag1 += s_red[f0+1]   + s_red[FF+f0+1]   + s_red[2*FF+f0+1];
        float2 o; o.x = ag0; o.y = ag1;
        *(float2*)&agg[row*FF + f0] = o;
    }
}

// ------- v = ssp(agg@f2out_w + b) @ dense_w + b ; x += v ; 8 rows/block -------
__global__ __launch_bounds__(256) void k_out(const float* __restrict__ agg,
                                             const float* __restrict__ f2w,
                                             const float* __restrict__ f2b,
                                             const float* __restrict__ dw,
                                             const float* __restrict__ db,
                                             float* __restrict__ x){
    __shared__ float sa[8][FF];
    __shared__ float st[8][FF];
    int tid = threadIdx.x;
    int rb = blockIdx.x*8;
    for(int i = tid; i < 8*FF; i += 256) sa[i>>7][i&(FF-1)] = agg[rb*FF + i];
    __syncthreads();
    int f = tid & (FF-1), rh = tid >> 7;
    float acc[4];
    {
        float bb = f2b[f];
        acc[0]=acc[1]=acc[2]=acc[3]=bb;
    }
    for(int kc = 0; kc < 32; kc++){
        float w0 = f2w[(4*kc+0)*FF+f];
        float w1 = f2w[(4*kc+1)*FF+f];
        float w2 = f2w[(4*kc+2)*FF+f];
        float w3 = f2w[(4*kc+3)*FF+f];
        #pragma unroll
        for(int rr = 0; rr < 4; rr++){
            float4 av = *(const float4*)&sa[rh+2*rr][4*kc];
            acc[rr] = fmaf(av.x,w0,fmaf(av.y,w1,fmaf(av.z,w2,fmaf(av.w,w3,acc[rr]))));
        }
    }
    #pragma unroll
    for(int rr = 0; rr < 4; rr++) st[rh+2*rr][f] = sspf(acc[rr]);
    __syncthreads();
    float a2[4];
    {
        float bd = db[f];
        a2[0]=a2[1]=a2[2]=a2[3]=bd;
    }
    for(int kc = 0; kc < 32; kc++){
        float w0 = dw[(4*kc+0)*FF+f];
        float w1 = dw[(4*kc+1)*FF+f];
        float w2 = dw[(4*kc+2)*FF+f];
        float w3 = dw[(4*kc+3)*FF+f];
        #pragma unroll
        for(int rr = 0; rr < 4; rr++){
            float4 tv = *(const float4*)&st[rh+2*rr][4*kc];
            a2[rr] = fmaf(tv.x,w0,fmaf(tv.y,w1,fmaf(tv.z,w2,fmaf(tv.w,w3,a2[rr]))));
        }
    }
    #pragma unroll
    for(int rr = 0; rr < 4; rr++) x[(rb+rh+2*rr)*FF + f] += a2[rr];
}

extern "C" void kernel_launch(void* const* d_in, const int* in_sizes, int n_in,
                              void* d_out, int out_size, void* d_ws, size_t ws_size,
                              hipStream_t stream) {
    const int*   zat  = (const int*)  d_in[0];
    const float* pos  = (const float*)d_in[1];
    const float* cell = (const float*)d_in[2];
    const float* coff = (const float*)d_in[3];
    const int*   nbr  = (const int*)  d_in[4];
    const float* mask = (const float*)d_in[5];
    const float* emb  = (const float*)d_in[6];
    const float* fw1  = (const float*)d_in[7];
    const float* fb1  = (const float*)d_in[8];
    const float* fw2  = (const float*)d_in[9];
    const float* fb2  = (const float*)d_in[10];
    const float* in2f = (const float*)d_in[11];
    const float* f2w  = (const float*)d_in[12];
    const float* f2b  = (const float*)d_in[13];
    const float* dw   = (const float*)d_in[14];
    const float* db   = (const float*)d_in[15];

    float* x    = (float*)d_out;              // x lives in d_out
    float* ws   = (float*)d_ws;
    float* rbuf = ws;                          // B*A*N
    float* cbuf = rbuf + BB*AA*NN;             // B*A*N
    float* ybuf = cbuf + BB*AA*NN;             // B*A*F
    float* abuf = ybuf + BB*AA*FF;             // B*A*F

    k_pre <<<BB*AA*NN/256, 256, 0, stream>>>(pos, cell, coff, nbr, mask, rbuf, cbuf);
    k_init<<<BB*AA*FF/256, 256, 0, stream>>>(zat, emb, x);

    for(int l = 0; l < 3; l++){
        k_in2f<<<BB*AA/8, 256, 0, stream>>>(x, in2f + l*FF*FF, ybuf);
        k_conv<<<BB*AA,   256, 0, stream>>>(rbuf, cbuf, nbr, ybuf,
                                            fw1 + l*NG*FF, fb1 + l*FF,
                                            fw2 + l*FF*FF, fb2 + l*FF, abuf);
        k_out <<<BB*AA/8, 256, 0, stream>>>(abuf, f2w + l*FF*FF, f2b + l*FF,
                                            dw + l*FF*FF, db + l*FF, x);
    }
}

// Round 2
// 261.502 us; speedup vs baseline: 5.0995x; 5.0995x over previous
//
#include <hip/hip_runtime.h>
#include <math.h>

#define BB 8
#define AA 1024
#define NN 64
#define FF 128
#define NG 25

#define WIDTH 0.2083333333f     /* 5/24 */
#define COEF  (-0.5f/(WIDTH*WIDTH))
#define COEF2 (COEF*1.44269504f)   /* for exp2 form */
#define PI_F  3.14159265358979f

typedef __attribute__((ext_vector_type(8))) short bf16x8;
typedef __attribute__((ext_vector_type(4))) short bf16x4;
typedef __attribute__((ext_vector_type(4))) float f32x4;

__device__ __forceinline__ short bf16r(float x){
    union { float f; unsigned u; } v; v.f = x;
    unsigned r = v.u + 0x7FFF + ((v.u >> 16) & 1);
    return (short)(r >> 16);
}

__device__ __forceinline__ float sspf(float x){
    // log(1+e^x) - log2 via native exp2/log2
    float ex = exp2f(x * 1.44269504f);
    return __log2f(1.f + ex) * 0.69314718f - 0.69314718f;
}

// ---------------- geometry precompute: masked r and C*mask ----------------
__global__ void k_pre(const float* __restrict__ pos, const float* __restrict__ cell,
                      const float* __restrict__ coff, const int* __restrict__ nbr,
                      const float* __restrict__ mask,
                      float* __restrict__ rbuf, float* __restrict__ cbuf){
    int flat = blockIdx.x*256 + threadIdx.x;         // < B*A*N
    int b = flat >> 16;
    int a = (flat >> 6) & (AA-1);
    int j = nbr[flat];
    const float* pi = pos + (b*AA + a)*3;
    const float* pj = pos + (b*AA + j)*3;
    const float* co = coff + (size_t)flat*3;
    const float* cl = cell + b*9;
    float ox = co[0]*cl[0] + co[1]*cl[3] + co[2]*cl[6];
    float oy = co[0]*cl[1] + co[1]*cl[4] + co[2]*cl[7];
    float oz = co[0]*cl[2] + co[1]*cl[5] + co[2]*cl[8];
    float vx = pj[0]-pi[0]+ox, vy = pj[1]-pi[1]+oy, vz = pj[2]-pi[2]+oz;
    float d2 = vx*vx + vy*vy + vz*vz;
    float m  = mask[flat];
    float r  = sqrtf(m > 0.f ? d2 : 1.0f) * m;
    float C  = 0.5f*(cosf(r*(PI_F/5.0f)) + 1.0f) * (r < 5.0f ? 1.f : 0.f);
    rbuf[flat] = r;
    cbuf[flat] = C*m;
}

// ---------------- x0 = embed[atomic_numbers] ----------------
__global__ void k_init(const int* __restrict__ z, const float* __restrict__ emb,
                       float* __restrict__ x){
    int idx = blockIdx.x*256 + threadIdx.x;          // < B*A*F
    int atom = idx >> 7;
    int f = idx & (FF-1);
    x[idx] = emb[z[atom]*FF + f];
}

// ------- pack fw1/fw2 (all 3 layers) into bf16 MFMA B-fragment order -------
// b1f: [l][nt=8][lane=64][i=8]   value = fw1[l][k=8q+i][16nt+m], 0 if k>=25
// b2f: [l][ks=4][nt=8][lane=64][i=8] value = fw2[l][32ks+8q+i][16nt+m]
__global__ void k_pack(const float* __restrict__ fw1, const float* __restrict__ fw2,
                       short* __restrict__ b1f, short* __restrict__ b2f){
    int idx = blockIdx.x*256 + threadIdx.x;          // < 3*16384
    {   // b2
        int l3 = idx / 16384, rem = idx & 16383;
        int ks = rem >> 12, nt = (rem >> 9) & 7, lane = (rem >> 3) & 63, i = rem & 7;
        int k = 32*ks + 8*(lane >> 4) + i;
        int f = 16*nt + (lane & 15);
        b2f[idx] = bf16r(fw2[(l3*FF + k)*FF + f]);
    }
    if(idx < 3*4096){   // b1
        int l3 = idx >> 12, rem = idx & 4095;
        int nt = rem >> 9, lane = (rem >> 3) & 63, i = rem & 7;
        int k = 8*(lane >> 4) + i;
        int f = 16*nt + (lane & 15);
        float v = (k < NG) ? fw1[(l3*NG + k)*FF + f] : 0.f;
        b1f[idx] = bf16r(v);
    }
}

// ---------------- y = x @ in2f_w (no bias); 8 rows per block ----------------
__global__ __launch_bounds__(256) void k_in2f(const float* __restrict__ x,
                                              const float* __restrict__ w,
                                              float* __restrict__ y){
    __shared__ float sx[8][FF];
    int tid = threadIdx.x;
    int rb = blockIdx.x*8;
    for(int i = tid; i < 8*FF; i += 256) sx[i>>7][i&(FF-1)] = x[rb*FF + i];
    __syncthreads();
    int f = tid & (FF-1), rh = tid >> 7;
    float acc[4] = {0.f,0.f,0.f,0.f};
    for(int kc = 0; kc < 32; kc++){
        float w0 = w[(4*kc+0)*FF+f];
        float w1 = w[(4*kc+1)*FF+f];
        float w2 = w[(4*kc+2)*FF+f];
        float w3 = w[(4*kc+3)*FF+f];
        #pragma unroll
        for(int rr = 0; rr < 4; rr++){
            float4 xv = *(const float4*)&sx[rh+2*rr][4*kc];
            acc[rr] = fmaf(xv.x,w0,fmaf(xv.y,w1,fmaf(xv.z,w2,fmaf(xv.w,w3,acc[rr]))));
        }
    }
    #pragma unroll
    for(int rr = 0; rr < 4; rr++) y[(rb+rh+2*rr)*FF + f] = acc[rr];
}

// ------- fused MFMA filter-net + CFConv aggregate; one block per atom -------
#define HSTR 132   /* s_H row stride in bf16 (264B): conflict-free writes, <=4-way reads */
__global__ __launch_bounds__(256) void k_conv(const float* __restrict__ rbuf,
                                              const float* __restrict__ cbuf,
                                              const int* __restrict__ nbr,
                                              const float* __restrict__ y,
                                              const short* __restrict__ b1f,
                                              const float* __restrict__ fb1,
                                              const short* __restrict__ b2f,
                                              const float* __restrict__ fb2,
                                              float* __restrict__ agg){
    __shared__ float s_r[NN];
    __shared__ float s_ce[NN];
    __shared__ int   s_j[NN];
    __shared__ short s_H[64*HSTR];
    __shared__ float s_red[3*FF];

    int tid = threadIdx.x;
    int row = blockIdx.x;              // b*A + a
    int b = row >> 10;

    if(tid < NN){
        s_r[tid]  = rbuf[row*NN + tid];
        s_ce[tid] = cbuf[row*NN + tid];
        s_j[tid]  = nbr[row*NN + tid];
    }
    __syncthreads();

    int lane = tid & 63, w = tid >> 6;
    int m = lane & 15, q = lane >> 4;
    int nrow = 16*w + m;               // A-fragment row for this lane (both GEMMs)

    // ---- A1 fragment in registers: f_ij[nrow][k], k = 8q+i (zero-pad k>=25) ----
    float rv = s_r[nrow];
    bf16x8 a1;
    #pragma unroll
    for(int i = 0; i < 8; i++){
        int k = 8*q + i;
        float d = rv - k*WIDTH;
        float v = (k < NG) ? exp2f(COEF2*d*d) : 0.f;
        a1[i] = bf16r(v);
    }

    // ---- GEMM1: H = ssp(f_ij @ fw1 + fb1), written to LDS (wave-local stripe) ----
    const bf16x8* b1v = (const bf16x8*)b1f;
    f32x4 zero = {0.f,0.f,0.f,0.f};
    #pragma unroll
    for(int nt = 0; nt < 8; nt++){
        f32x4 d1 = __builtin_amdgcn_mfma_f32_16x16x32_bf16(a1, b1v[nt*64 + lane], zero, 0, 0, 0);
        float bias = fb1[16*nt + m];
        #pragma unroll
        for(int j = 0; j < 4; j++){
            float h = sspf(d1[j] + bias);
            s_H[(16*w + 4*q + j)*HSTR + 16*nt + m] = bf16r(h);
        }
    }
    // no barrier: each wave reads only the 16-row stripe it wrote

    // ---- GEMM2: W = H @ fw2 (+fb2 in epilogue) ----
    const bf16x8* b2v = (const bf16x8*)b2f;
    f32x4 acc[8];
    #pragma unroll
    for(int nt = 0; nt < 8; nt++) acc[nt] = zero;
    #pragma unroll
    for(int ks = 0; ks < 4; ks++){
        const short* hp = &s_H[nrow*HSTR + 32*ks + 8*q];
        bf16x4 lo = *(const bf16x4*)hp;
        bf16x4 hi = *(const bf16x4*)(hp + 4);
        bf16x8 a2;
        a2[0]=lo[0]; a2[1]=lo[1]; a2[2]=lo[2]; a2[3]=lo[3];
        a2[4]=hi[0]; a2[5]=hi[1]; a2[6]=hi[2]; a2[7]=hi[3];
        #pragma unroll
        for(int nt = 0; nt < 8; nt++){
            acc[nt] = __builtin_amdgcn_mfma_f32_16x16x32_bf16(a2, b2v[(ks*8 + nt)*64 + lane], acc[nt], 0, 0, 0);
        }
    }

    // ---- epilogue + aggregate: part[nt] = sum_j (W+b2)*ce*y over this lane's rows ----
    float bias2[8];
    #pragma unroll
    for(int nt = 0; nt < 8; nt++) bias2[nt] = fb2[16*nt + m];
    float part[8] = {0,0,0,0,0,0,0,0};
    #pragma unroll
    for(int j = 0; j < 4; j++){
        int n = 16*w + 4*q + j;
        float ce = s_ce[n];
        const float* yrow = y + (size_t)(b*AA + s_j[n])*FF;
        #pragma unroll
        for(int nt = 0; nt < 8; nt++){
            float wv = acc[nt][j] + bias2[nt];
            part[nt] = fmaf(wv*ce, yrow[16*nt + m], part[nt]);
        }
    }
    // reduce over the 4 q-groups (rows within this wave's stripe)
    #pragma unroll
    for(int nt = 0; nt < 8; nt++){
        part[nt] += __shfl_xor(part[nt], 16);
        part[nt] += __shfl_xor(part[nt], 32);
    }
    // cross-wave combine
    if(w > 0 && q == 0){
        #pragma unroll
        for(int nt = 0; nt < 8; nt++) s_red[(w-1)*FF + 16*nt + m] = part[nt];
    }
    __syncthreads();
    if(w == 0 && q == 0){
        #pragma unroll
        for(int nt = 0; nt < 8; nt++){
            int f = 16*nt + m;
            agg[row*FF + f] = part[nt] + s_red[f] + s_red[FF+f] + s_red[2*FF+f];
        }
    }
}

// ------- v = ssp(agg@f2out_w + b) @ dense_w + b ; x += v ; 8 rows/block -------
__global__ __launch_bounds__(256) void k_out(const float* __restrict__ agg,
                                             const float* __restrict__ f2w,
                                             const float* __restrict__ f2b,
                                             const float* __restrict__ dw,
                                             const float* __restrict__ db,
                                             float* __restrict__ x){
    __shared__ float sa[8][FF];
    __shared__ float st[8][FF];
    int tid = threadIdx.x;
    int rb = blockIdx.x*8;
    for(int i = tid; i < 8*FF; i += 256) sa[i>>7][i&(FF-1)] = agg[rb*FF + i];
    __syncthreads();
    int f = tid & (FF-1), rh = tid >> 7;
    float acc[4];
    {
        float bb = f2b[f];
        acc[0]=acc[1]=acc[2]=acc[3]=bb;
    }
    for(int kc = 0; kc < 32; kc++){
        float w0 = f2w[(4*kc+0)*FF+f];
        float w1 = f2w[(4*kc+1)*FF+f];
        float w2 = f2w[(4*kc+2)*FF+f];
        float w3 = f2w[(4*kc+3)*FF+f];
        #pragma unroll
        for(int rr = 0; rr < 4; rr++){
            float4 av = *(const float4*)&sa[rh+2*rr][4*kc];
            acc[rr] = fmaf(av.x,w0,fmaf(av.y,w1,fmaf(av.z,w2,fmaf(av.w,w3,acc[rr]))));
        }
    }
    #pragma unroll
    for(int rr = 0; rr < 4; rr++) st[rh+2*rr][f] = sspf(acc[rr]);
    __syncthreads();
    float a2[4];
    {
        float bd = db[f];
        a2[0]=a2[1]=a2[2]=a2[3]=bd;
    }
    for(int kc = 0; kc < 32; kc++){
        float w0 = dw[(4*kc+0)*FF+f];
        float w1 = dw[(4*kc+1)*FF+f];
        float w2 = dw[(4*kc+2)*FF+f];
        float w3 = dw[(4*kc+3)*FF+f];
        #pragma unroll
        for(int rr = 0; rr < 4; rr++){
            float4 tv = *(const float4*)&st[rh+2*rr][4*kc];
            a2[rr] = fmaf(tv.x,w0,fmaf(tv.y,w1,fmaf(tv.z,w2,fmaf(tv.w,w3,a2[rr]))));
        }
    }
    #pragma unroll
    for(int rr = 0; rr < 4; rr++) x[(rb+rh+2*rr)*FF + f] += a2[rr];
}

extern "C" void kernel_launch(void* const* d_in, const int* in_sizes, int n_in,
                              void* d_out, int out_size, void* d_ws, size_t ws_size,
                              hipStream_t stream) {
    const int*   zat  = (const int*)  d_in[0];
    const float* pos  = (const float*)d_in[1];
    const float* cell = (const float*)d_in[2];
    const float* coff = (const float*)d_in[3];
    const int*   nbr  = (const int*)  d_in[4];
    const float* mask = (const float*)d_in[5];
    const float* emb  = (const float*)d_in[6];
    const float* fw1  = (const float*)d_in[7];
    const float* fb1  = (const float*)d_in[8];
    const float* fw2  = (const float*)d_in[9];
    const float* fb2  = (const float*)d_in[10];
    const float* in2f = (const float*)d_in[11];
    const float* f2w  = (const float*)d_in[12];
    const float* f2b  = (const float*)d_in[13];
    const float* dw   = (const float*)d_in[14];
    const float* db   = (const float*)d_in[15];

    float* x    = (float*)d_out;               // x lives in d_out
    float* ws   = (float*)d_ws;
    float* rbuf = ws;                          // B*A*N
    float* cbuf = rbuf + BB*AA*NN;             // B*A*N
    float* ybuf = cbuf + BB*AA*NN;             // B*A*F
    float* abuf = ybuf + BB*AA*FF;             // B*A*F
    short* b1fr = (short*)(abuf + BB*AA*FF);   // 3*4096 bf16
    short* b2fr = b1fr + 3*4096;               // 3*16384 bf16

    k_pre <<<BB*AA*NN/256, 256, 0, stream>>>(pos, cell, coff, nbr, mask, rbuf, cbuf);
    k_init<<<BB*AA*FF/256, 256, 0, stream>>>(zat, emb, x);
    k_pack<<<3*16384/256, 256, 0, stream>>>(fw1, fw2, b1fr, b2fr);

    for(int l = 0; l < 3; l++){
        k_in2f<<<BB*AA/8, 256, 0, stream>>>(x, in2f + l*FF*FF, ybuf);
        k_conv<<<BB*AA,   256, 0, stream>>>(rbuf, cbuf, nbr, ybuf,
                                            b1fr + l*4096, fb1 + l*FF,
                                            b2fr + l*16384, fb2 + l*FF, abuf);
        k_out <<<BB*AA/8, 256, 0, stream>>>(abuf, f2w + l*FF*FF, f2b + l*FF,
                                            dw + l*FF*FF, db + l*FF, x);
    }
}

// Round 3
// 187.131 us; speedup vs baseline: 7.1262x; 1.3974x over previous
//
#include <hip/hip_runtime.h>
#include <math.h>

#define BB 8
#define AA 1024
#define NN 64
#define FF 128
#define NG 25

#define WIDTH 0.2083333333f     /* 5/24 */
#define COEF  (-0.5f/(WIDTH*WIDTH))
#define PI_F  3.14159265358979f
#define CUTOFF 5.0f

#define KT 512
#define HT (CUTOFF/(KT-1))
#define INVH ((float)(KT-1)/CUTOFF)

__device__ __forceinline__ short bf16r(float x){
    union { float f; unsigned u; } v; v.f = x;
    unsigned r = v.u + 0x7FFF + ((v.u >> 16) & 1);
    return (short)(r >> 16);
}

__device__ __forceinline__ float sspf(float x){
    // accurate shifted softplus
    return fmaxf(x, 0.f) + log1pf(expf(-fabsf(x))) - 0.69314718056f;
}

// ---------------- geometry precompute: table coordinate u ----------------
__global__ void k_pre(const float* __restrict__ pos, const float* __restrict__ cell,
                      const float* __restrict__ coff, const int* __restrict__ nbr,
                      const float* __restrict__ mask,
                      float* __restrict__ ubuf){
    int flat = blockIdx.x*256 + threadIdx.x;         // < B*A*N
    int b = flat >> 16;
    int a = (flat >> 6) & (AA-1);
    int j = nbr[flat];
    const float* pi = pos + (b*AA + a)*3;
    const float* pj = pos + (b*AA + j)*3;
    const float* co = coff + (size_t)flat*3;
    const float* cl = cell + b*9;
    float ox = co[0]*cl[0] + co[1]*cl[3] + co[2]*cl[6];
    float oy = co[0]*cl[1] + co[1]*cl[4] + co[2]*cl[7];
    float oz = co[0]*cl[2] + co[1]*cl[5] + co[2]*cl[8];
    float vx = pj[0]-pi[0]+ox, vy = pj[1]-pi[1]+oy, vz = pj[2]-pi[2]+oz;
    float d2 = vx*vx + vy*vy + vz*vz;
    float m  = mask[flat];
    float r  = sqrtf(m > 0.f ? d2 : 1.0f) * m;
    // beyond-cutoff or masked-out -> last knot, where table value = 0
    float u  = (m > 0.f && r < CUTOFF) ? r * INVH : (float)(KT-1);
    ubuf[flat] = u;
}

// ---------------- x0 = embed[atomic_numbers] ----------------
__global__ void k_init(const int* __restrict__ z, const float* __restrict__ emb,
                       float* __restrict__ x){
    int idx = blockIdx.x*256 + threadIdx.x;          // < B*A*F
    int atom = idx >> 7;
    int f = idx & (FF-1);
    x[idx] = emb[z[atom]*FF + f];
}

// ---- build filter table: V[l][j][f] = (ssp(gauss(r_j)@fw1+b1)@fw2+b2)[f] * C(r_j) ----
__global__ __launch_bounds__(128) void k_table(const float* __restrict__ fw1,
                                               const float* __restrict__ fb1,
                                               const float* __restrict__ fw2,
                                               const float* __restrict__ fb2,
                                               float* __restrict__ V){
    __shared__ float sH[FF];
    int l = blockIdx.x >> 9;           // KT=512 knots per layer
    int j = blockIdx.x & (KT-1);
    int f = threadIdx.x;
    float r = j * HT;
    float z = fb1[l*FF + f];
    for(int g = 0; g < NG; g++){
        float d = r - g*WIDTH;
        z += expf(COEF*d*d) * fw1[(l*NG + g)*FF + f];
    }
    sH[f] = sspf(z);
    __syncthreads();
    float wv = fb2[l*FF + f];
    for(int k = 0; k < FF; k++)
        wv = fmaf(sH[k], fw2[(l*FF + k)*FF + f], wv);
    float C = (r < CUTOFF) ? 0.5f*(cosf(r*(PI_F/CUTOFF)) + 1.0f) : 0.f;
    V[(l*KT + j)*FF + f] = wv * C;
}

// ---- pack endpoint pairs: Tp[l][j][f] = (bf16 V[j][f], bf16 V[j+1][f]) in one u32 ----
__global__ void k_packT(const float* __restrict__ V, unsigned* __restrict__ Tp){
    int idx = blockIdx.x*256 + threadIdx.x;          // < 3*KT*FF
    int rem = idx & (KT*FF - 1);
    int nxt = (rem < (KT-1)*FF) ? FF : 0;            // last row duplicates itself
    unsigned lo = (unsigned short)bf16r(V[idx]);
    unsigned hi = (unsigned short)bf16r(V[idx + nxt]);
    Tp[idx] = lo | (hi << 16);
}

// ---------------- y = x @ in2f_w (no bias); 8 rows per block ----------------
__global__ __launch_bounds__(256) void k_in2f(const float* __restrict__ x,
                                              const float* __restrict__ w,
                                              float* __restrict__ y){
    __shared__ float sx[8][FF];
    int tid = threadIdx.x;
    int rb = blockIdx.x*8;
    for(int i = tid; i < 8*FF; i += 256) sx[i>>7][i&(FF-1)] = x[rb*FF + i];
    __syncthreads();
    int f = tid & (FF-1), rh = tid >> 7;
    float acc[4] = {0.f,0.f,0.f,0.f};
    for(int kc = 0; kc < 32; kc++){
        float w0 = w[(4*kc+0)*FF+f];
        float w1 = w[(4*kc+1)*FF+f];
        float w2 = w[(4*kc+2)*FF+f];
        float w3 = w[(4*kc+3)*FF+f];
        #pragma unroll
        for(int rr = 0; rr < 4; rr++){
            float4 xv = *(const float4*)&sx[rh+2*rr][4*kc];
            acc[rr] = fmaf(xv.x,w0,fmaf(xv.y,w1,fmaf(xv.z,w2,fmaf(xv.w,w3,acc[rr]))));
        }
    }
    #pragma unroll
    for(int rr = 0; rr < 4; rr++) y[(rb+rh+2*rr)*FF + f] = acc[rr];
}

// ------- CFConv via table lerp: agg[a,f] = sum_n lerp(Tp, u[a,n])[f] * y[j[a,n],f] -------
__global__ __launch_bounds__(256) void k_conv(const float* __restrict__ ubuf,
                                              const int* __restrict__ nbr,
                                              const float* __restrict__ y,
                                              const unsigned* __restrict__ Tp,
                                              float* __restrict__ agg){
    __shared__ float s_u[NN];
    __shared__ int   s_j[NN];
    __shared__ float s_red[3*FF];

    int tid = threadIdx.x;
    int row = blockIdx.x;              // b*A + a
    int b = row >> 10;

    if(tid < NN){
        s_u[tid] = ubuf[row*NN + tid];
        s_j[tid] = nbr[row*NN + tid];
    }
    __syncthreads();

    int l = tid & 63, w = tid >> 6;
    int f0 = 2*l;
    const float* yb = y + (size_t)b*AA*FF + f0;
    float acc0 = 0.f, acc1 = 0.f;

    #pragma unroll
    for(int t = 0; t < 16; t++){
        int n = 16*w + t;
        float u = s_u[n];
        int jn  = s_j[n];
        int iv = (int)u; iv = iv > KT-2 ? KT-2 : iv;
        float fr = u - (float)iv;
        uint2 tp = *(const uint2*)&Tp[iv*FF + f0];
        float2 yv = *(const float2*)&yb[(size_t)jn*FF];
        float lo0 = __uint_as_float(tp.x << 16);
        float hi0 = __uint_as_float(tp.x & 0xFFFF0000u);
        float lo1 = __uint_as_float(tp.y << 16);
        float hi1 = __uint_as_float(tp.y & 0xFFFF0000u);
        float w0 = fmaf(fr, hi0 - lo0, lo0);
        float w1 = fmaf(fr, hi1 - lo1, lo1);
        acc0 = fmaf(w0, yv.x, acc0);
        acc1 = fmaf(w1, yv.y, acc1);
    }

    if(w > 0){
        float2 p = {acc0, acc1};
        *(float2*)&s_red[(w-1)*FF + f0] = p;
    }
    __syncthreads();
    if(w == 0){
        acc0 += s_red[f0]   + s_red[FF+f0]   + s_red[2*FF+f0];
        acc1 += s_red[f0+1] + s_red[FF+f0+1] + s_red[2*FF+f0+1];
        float2 o = {acc0, acc1};
        *(float2*)&agg[row*FF + f0] = o;
    }
}

// ------- v = ssp(agg@f2out_w + b) @ dense_w + b ; x += v ; 8 rows/block -------
__global__ __launch_bounds__(256) void k_out(const float* __restrict__ agg,
                                             const float* __restrict__ f2w,
                                             const float* __restrict__ f2b,
                                             const float* __restrict__ dw,
                                             const float* __restrict__ db,
                                             float* __restrict__ x){
    __shared__ float sa[8][FF];
    __shared__ float st[8][FF];
    int tid = threadIdx.x;
    int rb = blockIdx.x*8;
    for(int i = tid; i < 8*FF; i += 256) sa[i>>7][i&(FF-1)] = agg[rb*FF + i];
    __syncthreads();
    int f = tid & (FF-1), rh = tid >> 7;
    float acc[4];
    {
        float bb = f2b[f];
        acc[0]=acc[1]=acc[2]=acc[3]=bb;
    }
    for(int kc = 0; kc < 32; kc++){
        float w0 = f2w[(4*kc+0)*FF+f];
        float w1 = f2w[(4*kc+1)*FF+f];
        float w2 = f2w[(4*kc+2)*FF+f];
        float w3 = f2w[(4*kc+3)*FF+f];
        #pragma unroll
        for(int rr = 0; rr < 4; rr++){
            float4 av = *(const float4*)&sa[rh+2*rr][4*kc];
            acc[rr] = fmaf(av.x,w0,fmaf(av.y,w1,fmaf(av.z,w2,fmaf(av.w,w3,acc[rr]))));
        }
    }
    #pragma unroll
    for(int rr = 0; rr < 4; rr++) st[rh+2*rr][f] = sspf(acc[rr]);
    __syncthreads();
    float a2[4];
    {
        float bd = db[f];
        a2[0]=a2[1]=a2[2]=a2[3]=bd;
    }
    for(int kc = 0; kc < 32; kc++){
        float w0 = dw[(4*kc+0)*FF+f];
        float w1 = dw[(4*kc+1)*FF+f];
        float w2 = dw[(4*kc+2)*FF+f];
        float w3 = dw[(4*kc+3)*FF+f];
        #pragma unroll
        for(int rr = 0; rr < 4; rr++){
            float4 tv = *(const float4*)&st[rh+2*rr][4*kc];
            a2[rr] = fmaf(tv.x,w0,fmaf(tv.y,w1,fmaf(tv.z,w2,fmaf(tv.w,w3,a2[rr]))));
        }
    }
    #pragma unroll
    for(int rr = 0; rr < 4; rr++) x[(rb+rh+2*rr)*FF + f] += a2[rr];
}

extern "C" void kernel_launch(void* const* d_in, const int* in_sizes, int n_in,
                              void* d_out, int out_size, void* d_ws, size_t ws_size,
                              hipStream_t stream) {
    const int*   zat  = (const int*)  d_in[0];
    const float* pos  = (const float*)d_in[1];
    const float* cell = (const float*)d_in[2];
    const float* coff = (const float*)d_in[3];
    const int*   nbr  = (const int*)  d_in[4];
    const float* mask = (const float*)d_in[5];
    const float* emb  = (const float*)d_in[6];
    const float* fw1  = (const float*)d_in[7];
    const float* fb1  = (const float*)d_in[8];
    const float* fw2  = (const float*)d_in[9];
    const float* fb2  = (const float*)d_in[10];
    const float* in2f = (const float*)d_in[11];
    const float* f2w  = (const float*)d_in[12];
    const float* f2b  = (const float*)d_in[13];
    const float* dw   = (const float*)d_in[14];
    const float* db   = (const float*)d_in[15];

    float* x    = (float*)d_out;               // x lives in d_out
    float* ws   = (float*)d_ws;
    float* ubuf = ws;                          // B*A*N
    float* ybuf = ubuf + BB*AA*NN;             // B*A*F
    float* abuf = ybuf + BB*AA*FF;             // B*A*F
    float* Vbuf = abuf + BB*AA*FF;             // 3*KT*FF
    unsigned* Tp = (unsigned*)(Vbuf + 3*KT*FF);// 3*KT*FF u32

    k_pre  <<<BB*AA*NN/256, 256, 0, stream>>>(pos, cell, coff, nbr, mask, ubuf);
    k_init <<<BB*AA*FF/256, 256, 0, stream>>>(zat, emb, x);
    k_table<<<3*KT, 128, 0, stream>>>(fw1, fb1, fw2, fb2, Vbuf);
    k_packT<<<3*KT*FF/256, 256, 0, stream>>>(Vbuf, Tp);

    for(int l = 0; l < 3; l++){
        k_in2f<<<BB*AA/8, 256, 0, stream>>>(x, in2f + l*FF*FF, ybuf);
        k_conv<<<BB*AA,   256, 0, stream>>>(ubuf, nbr, ybuf, Tp + l*KT*FF, abuf);
        k_out <<<BB*AA/8, 256, 0, stream>>>(abuf, f2w + l*FF*FF, f2b + l*FF,
                                            dw + l*FF*FF, db + l*FF, x);
    }
}

// Round 4
// 160.587 us; speedup vs baseline: 8.3041x; 1.1653x over previous
//
#include <hip/hip_runtime.h>
#include <hip/hip_fp16.h>
#include <math.h>

#define BB 8
#define AA 1024
#define NN 64
#define FF 128
#define NG 25

#define WIDTH 0.2083333333f     /* 5/24 */
#define COEF  (-0.5f/(WIDTH*WIDTH))
#define PI_F  3.14159265358979f
#define CUTOFF 5.0f

#define KT 2048
#define HT (CUTOFF/(KT-1))
#define INVH ((float)(KT-1)/CUTOFF)

__device__ __forceinline__ float sspf(float x){
    return fmaxf(x, 0.f) + log1pf(expf(-fabsf(x))) - 0.69314718056f;
}

__device__ __forceinline__ __half2 h2bc(unsigned u){
    union { unsigned u; __half2 h; } v; v.u = u; return v.h;
}

// ---- geometry precompute: code = nearest-knot index | (neighbor << 16) ----
__global__ void k_pre(const float* __restrict__ pos, const float* __restrict__ cell,
                      const float* __restrict__ coff, const int* __restrict__ nbr,
                      const float* __restrict__ mask,
                      unsigned* __restrict__ codes){
    int flat = blockIdx.x*256 + threadIdx.x;         // < B*A*N
    int b = flat >> 16;
    int a = (flat >> 6) & (AA-1);
    int j = nbr[flat];
    const float* pi = pos + (b*AA + a)*3;
    const float* pj = pos + (b*AA + j)*3;
    const float* co = coff + (size_t)flat*3;
    const float* cl = cell + b*9;
    float ox = co[0]*cl[0] + co[1]*cl[3] + co[2]*cl[6];
    float oy = co[0]*cl[1] + co[1]*cl[4] + co[2]*cl[7];
    float oz = co[0]*cl[2] + co[1]*cl[5] + co[2]*cl[8];
    float vx = pj[0]-pi[0]+ox, vy = pj[1]-pi[1]+oy, vz = pj[2]-pi[2]+oz;
    float d2 = vx*vx + vy*vy + vz*vz;
    float m  = mask[flat];
    float r  = sqrtf(m > 0.f ? d2 : 1.0f) * m;
    int iv;
    if(m > 0.f && r < CUTOFF){
        iv = (int)(r*INVH + 0.5f);
        if(iv > KT-1) iv = KT-1;
    } else {
        iv = KT-1;                 // T[KT-1] = 0 (C(cutoff)=0)
    }
    codes[flat] = (unsigned)iv | ((unsigned)j << 16);
}

// ---- filter table (nearest): T[l][j][f] = fp16( (ssp(g(r_j)@fw1+b1)@fw2+b2)[f] * C(r_j) ) ----
__global__ __launch_bounds__(128) void k_table(const float* __restrict__ fw1,
                                               const float* __restrict__ fb1,
                                               const float* __restrict__ fw2,
                                               const float* __restrict__ fb2,
                                               __half* __restrict__ T){
    __shared__ float sH[FF];
    int l = blockIdx.x >> 11;          // KT=2048 knots per layer
    int j = blockIdx.x & (KT-1);
    int f = threadIdx.x;
    float r = j * HT;
    float z = fb1[l*FF + f];
    for(int g = 0; g < NG; g++){
        float d = r - g*WIDTH;
        z += expf(COEF*d*d) * fw1[(l*NG + g)*FF + f];
    }
    sH[f] = sspf(z);
    __syncthreads();
    float wv = fb2[l*FF + f];
    for(int k = 0; k < FF; k++)
        wv = fmaf(sH[k], fw2[(l*FF + k)*FF + f], wv);
    float C = (r < CUTOFF) ? 0.5f*(cosf(r*(PI_F/CUTOFF)) + 1.0f) : 0.f;
    T[(l*KT + j)*FF + f] = __float2half(wv * C);
}

// ---- x0 = embed[z]; y0 = x0 @ in2f[0] (fp16) ; 8 atoms / 512 threads ----
__global__ __launch_bounds__(512) void k_first(const int* __restrict__ z,
                                               const float* __restrict__ emb,
                                               const float* __restrict__ w,
                                               float* __restrict__ x,
                                               __half* __restrict__ y){
    __shared__ float sx[8][FF];
    int tid = threadIdx.x;
    int row0 = blockIdx.x*8;
    for(int i = tid; i < 8*FF; i += 512){
        int rr = i >> 7, f = i & (FF-1);
        float v = emb[z[row0+rr]*FF + f];
        sx[rr][f] = v;
        x[(row0+rr)*FF + f] = v;
    }
    __syncthreads();
    int f = tid & (FF-1), rh = tid >> 7;      // rows rh, rh+4
    float a0 = 0.f, a1 = 0.f;
    for(int kc = 0; kc < 32; kc++){
        float w0 = w[(4*kc+0)*FF+f];
        float w1 = w[(4*kc+1)*FF+f];
        float w2 = w[(4*kc+2)*FF+f];
        float w3 = w[(4*kc+3)*FF+f];
        float4 pa = *(const float4*)&sx[rh][4*kc];
        float4 pb = *(const float4*)&sx[rh+4][4*kc];
        a0 = fmaf(pa.x,w0,fmaf(pa.y,w1,fmaf(pa.z,w2,fmaf(pa.w,w3,a0))));
        a1 = fmaf(pb.x,w0,fmaf(pb.y,w1,fmaf(pb.z,w2,fmaf(pb.w,w3,a1))));
    }
    y[(row0+rh)*FF + f]   = __float2half(a0);
    y[(row0+rh+4)*FF + f] = __float2half(a1);
}

// ---- fused layer: conv (table-gather) + f2out(ssp) + dense + residual + next in2f ----
// 8 atoms per block, 512 threads (8 waves; conv: one wave per atom)
__global__ __launch_bounds__(512) void k_layer(const unsigned* __restrict__ codes,
                                               const __half* __restrict__ Tl,
                                               const __half* __restrict__ yin,
                                               const float* __restrict__ f2w,
                                               const float* __restrict__ f2b,
                                               const float* __restrict__ dw,
                                               const float* __restrict__ db,
                                               const float* __restrict__ wnext,
                                               float* __restrict__ x,
                                               __half* __restrict__ ynext){
    __shared__ unsigned s_code[512];
    __shared__ float s_agg[8][FF];
    __shared__ float s_t[8][FF];

    int tid = threadIdx.x;
    int row0 = blockIdx.x*8;
    int b = row0 >> 10;

    s_code[tid] = codes[row0*NN + tid];
    __syncthreads();

    // ---- conv: wave wv handles atom row0+wv; 2 neighbors x 32 lanes x 4 feats ----
    int wv = tid >> 6, lane = tid & 63;
    int hf = lane >> 5, fl = lane & 31, f0 = 4*fl;
    const __half* yb = yin + (size_t)b*AA*FF + f0;
    const __half* tb = Tl + f0;
    __half2 hz = __float2half2_rn(0.f);
    __half2 a0 = hz, a1 = hz;
    float c0 = 0.f, c1 = 0.f, c2 = 0.f, c3 = 0.f;
    #pragma unroll 8
    for(int t = 0; t < 32; t++){
        unsigned code = s_code[wv*64 + 2*t + hf];
        int iv = code & 0xFFFF;
        int j  = code >> 16;
        uint2 yv = *(const uint2*)(yb + ((size_t)j  << 7));
        uint2 tv = *(const uint2*)(tb + ((size_t)iv << 7));
        a0 = __hfma2(h2bc(tv.x), h2bc(yv.x), a0);
        a1 = __hfma2(h2bc(tv.y), h2bc(yv.y), a1);
        if((t & 7) == 7){   // flush fp16 accumulators to fp32 every 8 neighbors
            float2 p0 = __half22float2(a0);
            float2 p1 = __half22float2(a1);
            c0 += p0.x; c1 += p0.y; c2 += p1.x; c3 += p1.y;
            a0 = hz; a1 = hz;
        }
    }
    c0 += __shfl_xor(c0, 32);
    c1 += __shfl_xor(c1, 32);
    c2 += __shfl_xor(c2, 32);
    c3 += __shfl_xor(c3, 32);
    if(hf == 0){
        s_agg[wv][f0]   = c0;
        s_agg[wv][f0+1] = c1;
        s_agg[wv][f0+2] = c2;
        s_agg[wv][f0+3] = c3;
    }
    __syncthreads();

    // ---- GEMM1: t = ssp(agg @ f2w + f2b) ----
    int f = tid & (FF-1), rh = tid >> 7;      // rows rh, rh+4
    float g0 = f2b[f], g1 = g0;
    for(int kc = 0; kc < 32; kc++){
        float w0 = f2w[(4*kc+0)*FF+f];
        float w1 = f2w[(4*kc+1)*FF+f];
        float w2 = f2w[(4*kc+2)*FF+f];
        float w3 = f2w[(4*kc+3)*FF+f];
        float4 pa = *(const float4*)&s_agg[rh][4*kc];
        float4 pb = *(const float4*)&s_agg[rh+4][4*kc];
        g0 = fmaf(pa.x,w0,fmaf(pa.y,w1,fmaf(pa.z,w2,fmaf(pa.w,w3,g0))));
        g1 = fmaf(pb.x,w0,fmaf(pb.y,w1,fmaf(pb.z,w2,fmaf(pb.w,w3,g1))));
    }
    s_t[rh][f]   = sspf(g0);
    s_t[rh+4][f] = sspf(g1);
    __syncthreads();

    // ---- GEMM2: v = t @ dw + db ; xnew = x + v (write back, stash in s_agg) ----
    float v0 = db[f], v1 = v0;
    for(int kc = 0; kc < 32; kc++){
        float w0 = dw[(4*kc+0)*FF+f];
        float w1 = dw[(4*kc+1)*FF+f];
        float w2 = dw[(4*kc+2)*FF+f];
        float w3 = dw[(4*kc+3)*FF+f];
        float4 pa = *(const float4*)&s_t[rh][4*kc];
        float4 pb = *(const float4*)&s_t[rh+4][4*kc];
        v0 = fmaf(pa.x,w0,fmaf(pa.y,w1,fmaf(pa.z,w2,fmaf(pa.w,w3,v0))));
        v1 = fmaf(pb.x,w0,fmaf(pb.y,w1,fmaf(pb.z,w2,fmaf(pb.w,w3,v1))));
    }
    float xn0 = x[(row0+rh)*FF + f]   + v0;
    float xn1 = x[(row0+rh+4)*FF + f] + v1;
    x[(row0+rh)*FF + f]   = xn0;
    x[(row0+rh+4)*FF + f] = xn1;
    if(wnext){
        s_agg[rh][f]   = xn0;
        s_agg[rh+4][f] = xn1;
        __syncthreads();
        // ---- GEMM3: ynext = xnew @ wnext (fp16 out) ----
        float y0 = 0.f, y1 = 0.f;
        for(int kc = 0; kc < 32; kc++){
            float w0 = wnext[(4*kc+0)*FF+f];
            float w1 = wnext[(4*kc+1)*FF+f];
            float w2 = wnext[(4*kc+2)*FF+f];
            float w3 = wnext[(4*kc+3)*FF+f];
            float4 pa = *(const float4*)&s_agg[rh][4*kc];
            float4 pb = *(const float4*)&s_agg[rh+4][4*kc];
            y0 = fmaf(pa.x,w0,fmaf(pa.y,w1,fmaf(pa.z,w2,fmaf(pa.w,w3,y0))));
            y1 = fmaf(pb.x,w0,fmaf(pb.y,w1,fmaf(pb.z,w2,fmaf(pb.w,w3,y1))));
        }
        ynext[(row0+rh)*FF + f]   = __float2half(y0);
        ynext[(row0+rh+4)*FF + f] = __float2half(y1);
    }
}

extern "C" void kernel_launch(void* const* d_in, const int* in_sizes, int n_in,
                              void* d_out, int out_size, void* d_ws, size_t ws_size,
                              hipStream_t stream) {
    const int*   zat  = (const int*)  d_in[0];
    const float* pos  = (const float*)d_in[1];
    const float* cell = (const float*)d_in[2];
    const float* coff = (const float*)d_in[3];
    const int*   nbr  = (const int*)  d_in[4];
    const float* mask = (const float*)d_in[5];
    const float* emb  = (const float*)d_in[6];
    const float* fw1  = (const float*)d_in[7];
    const float* fb1  = (const float*)d_in[8];
    const float* fw2  = (const float*)d_in[9];
    const float* fb2  = (const float*)d_in[10];
    const float* in2f = (const float*)d_in[11];
    const float* f2w  = (const float*)d_in[12];
    const float* f2b  = (const float*)d_in[13];
    const float* dw   = (const float*)d_in[14];
    const float* db   = (const float*)d_in[15];

    float* x = (float*)d_out;                      // x lives in d_out
    unsigned* codes = (unsigned*)d_ws;             // B*A*N u32         (2 MB)
    __half* Tb = (__half*)(codes + BB*AA*NN);      // 3*KT*FF half      (1.5 MB)
    __half* yA = Tb + 3*KT*FF;                     // B*A*F half        (2 MB)
    __half* yB = yA + BB*AA*FF;                    // B*A*F half        (2 MB)

    k_pre  <<<BB*AA*NN/256, 256, 0, stream>>>(pos, cell, coff, nbr, mask, codes);
    k_table<<<3*KT, 128, 0, stream>>>(fw1, fb1, fw2, fb2, Tb);
    k_first<<<BB*AA/8, 512, 0, stream>>>(zat, emb, in2f, x, yA);

    k_layer<<<BB*AA/8, 512, 0, stream>>>(codes, Tb,           yA,
                                         f2w,          f2b,          dw,          db,
                                         in2f + 1*FF*FF, x, yB);
    k_layer<<<BB*AA/8, 512, 0, stream>>>(codes, Tb + KT*FF,   yB,
                                         f2w + FF*FF,  f2b + FF,     dw + FF*FF,  db + FF,
                                         in2f + 2*FF*FF, x, yA);
    k_layer<<<BB*AA/8, 512, 0, stream>>>(codes, Tb + 2*KT*FF, yA,
                                         f2w + 2*FF*FF, f2b + 2*FF,  dw + 2*FF*FF, db + 2*FF,
                                         nullptr, x, nullptr);
}

// Round 5
// 115.566 us; speedup vs baseline: 11.5391x; 1.3896x over previous
//
#include <hip/hip_runtime.h>
#include <hip/hip_fp16.h>
#include <math.h>

#define BB 8
#define AA 1024
#define NN 64
#define FF 128
#define NG 25

#define WIDTH 0.2083333333f     /* 5/24 */
#define COEF  (-0.5f/(WIDTH*WIDTH))
#define PI_F  3.14159265358979f
#define CUTOFF 5.0f

#define KT 2048
#define HT (CUTOFF/(KT-1))
#define INVH ((float)(KT-1)/CUTOFF)

#define STR 132   /* LDS bf16 row stride (264 B) — round-2 verified conflict-free */

typedef __attribute__((ext_vector_type(8))) short bf16x8;
typedef __attribute__((ext_vector_type(4))) short bf16x4;
typedef __attribute__((ext_vector_type(4))) float f32x4;

__device__ __forceinline__ float sspf(float x){
    return fmaxf(x, 0.f) + log1pf(expf(-fabsf(x))) - 0.69314718056f;
}
__device__ __forceinline__ short bf16r(float x){
    union { float f; unsigned u; } v; v.f = x;
    unsigned r = v.u + 0x7FFF + ((v.u >> 16) & 1);
    return (short)(r >> 16);
}
__device__ __forceinline__ __half2 h2bc(unsigned u){
    union { unsigned u; __half2 h; } v; v.u = u; return v.h;
}

// ---- geometry precompute: code = nearest-knot index | (neighbor << 16) ----
__global__ void k_pre(const float* __restrict__ pos, const float* __restrict__ cell,
                      const float* __restrict__ coff, const int* __restrict__ nbr,
                      const float* __restrict__ mask,
                      unsigned* __restrict__ codes){
    int flat = blockIdx.x*256 + threadIdx.x;         // < B*A*N
    int b = flat >> 16;
    int a = (flat >> 6) & (AA-1);
    int j = nbr[flat];
    const float* pi = pos + (b*AA + a)*3;
    const float* pj = pos + (b*AA + j)*3;
    const float* co = coff + (size_t)flat*3;
    const float* cl = cell + b*9;
    float ox = co[0]*cl[0] + co[1]*cl[3] + co[2]*cl[6];
    float oy = co[0]*cl[1] + co[1]*cl[4] + co[2]*cl[7];
    float oz = co[0]*cl[2] + co[1]*cl[5] + co[2]*cl[8];
    float vx = pj[0]-pi[0]+ox, vy = pj[1]-pi[1]+oy, vz = pj[2]-pi[2]+oz;
    float d2 = vx*vx + vy*vy + vz*vz;
    float m  = mask[flat];
    float r  = sqrtf(m > 0.f ? d2 : 1.0f) * m;
    int iv;
    if(m > 0.f && r < CUTOFF){
        iv = (int)(r*INVH + 0.5f);
        if(iv > KT-1) iv = KT-1;
    } else {
        iv = KT-1;                 // T[KT-1] = 0 (C(cutoff)=0)
    }
    codes[flat] = (unsigned)iv | ((unsigned)j << 16);
}

// ---- filter table: T[l][j][f] = fp16( (ssp(g(r_j)@fw1+b1)@fw2+b2)[f] * C(r_j) ) ----
__global__ __launch_bounds__(128) void k_table(const float* __restrict__ fw1,
                                               const float* __restrict__ fb1,
                                               const float* __restrict__ fw2,
                                               const float* __restrict__ fb2,
                                               __half* __restrict__ T){
    __shared__ float sH[FF];
    int l = blockIdx.x >> 11;
    int j = blockIdx.x & (KT-1);
    int f = threadIdx.x;
    float r = j * HT;
    float z = fb1[l*FF + f];
    for(int g = 0; g < NG; g++){
        float d = r - g*WIDTH;
        z += expf(COEF*d*d) * fw1[(l*NG + g)*FF + f];
    }
    sH[f] = sspf(z);
    __syncthreads();
    float wv = fb2[l*FF + f];
    for(int k = 0; k < FF; k++)
        wv = fmaf(sH[k], fw2[(l*FF + k)*FF + f], wv);
    float C = (r < CUTOFF) ? 0.5f*(cosf(r*(PI_F/CUTOFF)) + 1.0f) : 0.f;
    T[(l*KT + j)*FF + f] = __float2half(wv * C);
}

// ---- pack 8 weight matrices into bf16 MFMA B-fragment order ----
// id 0..2: f2out_w[l]; 3..5: dense_w[l]; 6,7: in2f_w[1],in2f_w[2]
// out[id][ks][nt][lane][i] = W[32ks+8(lane>>4)+i][16nt+(lane&15)]
__global__ void k_packW(const float* __restrict__ f2w, const float* __restrict__ dw,
                        const float* __restrict__ in2f, short* __restrict__ out){
    int idx = blockIdx.x*256 + threadIdx.x;          // < 8*16384
    int id = idx >> 14, rem = idx & 16383;
    int ks = rem >> 12, nt = (rem >> 9) & 7, lane = (rem >> 3) & 63, i = rem & 7;
    int k = 32*ks + 8*(lane >> 4) + i;
    int f = 16*nt + (lane & 15);
    const float* src = (id < 3) ? f2w + id*16384
                     : (id < 6) ? dw  + (id-3)*16384
                                : in2f + (id-5)*16384;
    out[idx] = bf16r(src[k*FF + f]);
}

// ---- x0 = embed[z]; y0 = x0 @ in2f[0] (fp16) ; 8 atoms / 512 threads ----
__global__ __launch_bounds__(512) void k_first(const int* __restrict__ z,
                                               const float* __restrict__ emb,
                                               const float* __restrict__ w,
                                               float* __restrict__ x,
                                               __half* __restrict__ y){
    __shared__ float sx[8][FF];
    int tid = threadIdx.x;
    int row0 = blockIdx.x*8;
    for(int i = tid; i < 8*FF; i += 512){
        int rr = i >> 7, f = i & (FF-1);
        float v = emb[z[row0+rr]*FF + f];
        sx[rr][f] = v;
        x[(row0+rr)*FF + f] = v;
    }
    __syncthreads();
    int f = tid & (FF-1), rh = tid >> 7;
    float a0 = 0.f, a1 = 0.f;
    for(int kc = 0; kc < 32; kc++){
        float w0 = w[(4*kc+0)*FF+f];
        float w1 = w[(4*kc+1)*FF+f];
        float w2 = w[(4*kc+2)*FF+f];
        float w3 = w[(4*kc+3)*FF+f];
        float4 pa = *(const float4*)&sx[rh][4*kc];
        float4 pb = *(const float4*)&sx[rh+4][4*kc];
        a0 = fmaf(pa.x,w0,fmaf(pa.y,w1,fmaf(pa.z,w2,fmaf(pa.w,w3,a0))));
        a1 = fmaf(pb.x,w0,fmaf(pb.y,w1,fmaf(pb.z,w2,fmaf(pb.w,w3,a1))));
    }
    y[(row0+rh)*FF + f]   = __float2half(a0);
    y[(row0+rh+4)*FF + f] = __float2half(a1);
}

// ---- fused layer, MFMA edition: 16 atoms / 512 threads / 8 waves ----
// conv (fp16 table-gather) -> GEMM1 ssp -> GEMM2 + residual -> GEMM3 (next in2f)
__global__ __launch_bounds__(512) void k_layerM(const unsigned* __restrict__ codes,
                                                const __half* __restrict__ Tl,
                                                const __half* __restrict__ yin,
                                                const short* __restrict__ w1p,
                                                const float* __restrict__ f2b,
                                                const short* __restrict__ w2p,
                                                const float* __restrict__ db,
                                                const short* __restrict__ w3p,
                                                float* __restrict__ x,
                                                __half* __restrict__ ynext){
    __shared__ unsigned s_code[16*NN];
    __shared__ short s_a[16*STR];
    __shared__ short s_t[16*STR];

    int tid = threadIdx.x, wv = tid >> 6, lane = tid & 63;
    int m = lane & 15, q = lane >> 4;
    int row0 = blockIdx.x*16, b = blockIdx.x >> 6;
    int col = 16*wv + m;

    // ---- prefetch: weight fragments, biases, residual (latency hides under conv) ----
    const bf16x8* w1v = (const bf16x8*)w1p;
    const bf16x8* w2v = (const bf16x8*)w2p;
    const bf16x8* w3v = (const bf16x8*)w3p;
    bf16x8 wf1[4], wf2[4], wf3[4];
    #pragma unroll
    for(int ks = 0; ks < 4; ks++){
        wf1[ks] = w1v[(ks*8 + wv)*64 + lane];
        wf2[ks] = w2v[(ks*8 + wv)*64 + lane];
    }
    if(w3p){
        #pragma unroll
        for(int ks = 0; ks < 4; ks++) wf3[ks] = w3v[(ks*8 + wv)*64 + lane];
    }
    float bias1 = f2b[col], bias2 = db[col];
    float xr[4];
    #pragma unroll
    for(int j = 0; j < 4; j++) xr[j] = x[(row0 + 4*q + j)*FF + col];

    *(uint2*)&s_code[2*tid] = *(const uint2*)&codes[row0*NN + 2*tid];
    __syncthreads();

    // ---- conv: wave handles atoms 2wv, 2wv+1 interleaved; half-wave = 1 neighbor ----
    int hf = lane >> 5, fl = lane & 31, f0 = 4*fl;
    const __half* yb = yin + ((size_t)b*AA << 7) + f0;
    const __half* tb = Tl + f0;
    int a0 = 2*wv, a1 = 2*wv + 1;
    __half2 hz = __float2half2_rn(0.f);
    __half2 p00 = hz, p01 = hz, p10 = hz, p11 = hz;
    float c[8] = {0,0,0,0,0,0,0,0};
    #pragma unroll 8
    for(int t = 0; t < 32; t++){
        unsigned ca = s_code[a0*NN + 2*t + hf];
        unsigned cb = s_code[a1*NN + 2*t + hf];
        uint2 tva = *(const uint2*)(tb + ((ca & 0xFFFFu) << 7));
        uint2 yva = *(const uint2*)(yb + ((size_t)(ca >> 16) << 7));
        uint2 tvb = *(const uint2*)(tb + ((cb & 0xFFFFu) << 7));
        uint2 yvb = *(const uint2*)(yb + ((size_t)(cb >> 16) << 7));
        p00 = __hfma2(h2bc(tva.x), h2bc(yva.x), p00);
        p01 = __hfma2(h2bc(tva.y), h2bc(yva.y), p01);
        p10 = __hfma2(h2bc(tvb.x), h2bc(yvb.x), p10);
        p11 = __hfma2(h2bc(tvb.y), h2bc(yvb.y), p11);
        if((t & 7) == 7){
            float2 u0 = __half22float2(p00), u1 = __half22float2(p01);
            float2 u2 = __half22float2(p10), u3 = __half22float2(p11);
            c[0] += u0.x; c[1] += u0.y; c[2] += u1.x; c[3] += u1.y;
            c[4] += u2.x; c[5] += u2.y; c[6] += u3.x; c[7] += u3.y;
            p00 = hz; p01 = hz; p10 = hz; p11 = hz;
        }
    }
    #pragma unroll
    for(int i = 0; i < 8; i++) c[i] += __shfl_xor(c[i], 32);
    if(hf == 0){
        unsigned pk01 = (unsigned short)bf16r(c[0]) | ((unsigned)(unsigned short)bf16r(c[1]) << 16);
        unsigned pk23 = (unsigned short)bf16r(c[2]) | ((unsigned)(unsigned short)bf16r(c[3]) << 16);
        unsigned pk45 = (unsigned short)bf16r(c[4]) | ((unsigned)(unsigned short)bf16r(c[5]) << 16);
        unsigned pk67 = (unsigned short)bf16r(c[6]) | ((unsigned)(unsigned short)bf16r(c[7]) << 16);
        uint2 w0 = {pk01, pk23}, w1 = {pk45, pk67};
        *(uint2*)&s_a[a0*STR + f0] = w0;
        *(uint2*)&s_a[a1*STR + f0] = w1;
    }
    __syncthreads();

    // ---- GEMM1: t = ssp(agg @ f2w + f2b) ----
    f32x4 acc = {bias1, bias1, bias1, bias1};
    #pragma unroll
    for(int ks = 0; ks < 4; ks++){
        const short* ap = s_a + m*STR + 32*ks + 8*q;
        bf16x4 lo = *(const bf16x4*)ap;
        bf16x4 hi = *(const bf16x4*)(ap + 4);
        bf16x8 af;
        af[0]=lo[0]; af[1]=lo[1]; af[2]=lo[2]; af[3]=lo[3];
        af[4]=hi[0]; af[5]=hi[1]; af[6]=hi[2]; af[7]=hi[3];
        acc = __builtin_amdgcn_mfma_f32_16x16x32_bf16(af, wf1[ks], acc, 0, 0, 0);
    }
    #pragma unroll
    for(int j = 0; j < 4; j++)
        s_t[(4*q + j)*STR + col] = bf16r(sspf(acc[j]));
    __syncthreads();

    // ---- GEMM2: v = t @ dw + db ; xnew = x + v ----
    f32x4 a2 = {bias2, bias2, bias2, bias2};
    #pragma unroll
    for(int ks = 0; ks < 4; ks++){
        const short* ap = s_t + m*STR + 32*ks + 8*q;
        bf16x4 lo = *(const bf16x4*)ap;
        bf16x4 hi = *(const bf16x4*)(ap + 4);
        bf16x8 af;
        af[0]=lo[0]; af[1]=lo[1]; af[2]=lo[2]; af[3]=lo[3];
        af[4]=hi[0]; af[5]=hi[1]; af[6]=hi[2]; af[7]=hi[3];
        a2 = __builtin_amdgcn_mfma_f32_16x16x32_bf16(af, wf2[ks], a2, 0, 0, 0);
    }
    float xn[4];
    #pragma unroll
    for(int j = 0; j < 4; j++){
        xn[j] = xr[j] + a2[j];
        x[(row0 + 4*q + j)*FF + col] = xn[j];
    }
    if(w3p){
        // s_a's last reader was GEMM1 (pre-barrier) -> safe to overwrite now
        #pragma unroll
        for(int j = 0; j < 4; j++)
            s_a[(4*q + j)*STR + col] = bf16r(xn[j]);
        __syncthreads();
        // ---- GEMM3: ynext = xnew @ in2f_next (fp16 out) ----
        f32x4 a3 = {0.f, 0.f, 0.f, 0.f};
        #pragma unroll
        for(int ks = 0; ks < 4; ks++){
            const short* ap = s_a + m*STR + 32*ks + 8*q;
            bf16x4 lo = *(const bf16x4*)ap;
            bf16x4 hi = *(const bf16x4*)(ap + 4);
            bf16x8 af;
            af[0]=lo[0]; af[1]=lo[1]; af[2]=lo[2]; af[3]=lo[3];
            af[4]=hi[0]; af[5]=hi[1]; af[6]=hi[2]; af[7]=hi[3];
            a3 = __builtin_amdgcn_mfma_f32_16x16x32_bf16(af, wf3[ks], a3, 0, 0, 0);
        }
        #pragma unroll
        for(int j = 0; j < 4; j++)
            ynext[(row0 + 4*q + j)*FF + col] = __float2half(a3[j]);
    }
}

extern "C" void kernel_launch(void* const* d_in, const int* in_sizes, int n_in,
                              void* d_out, int out_size, void* d_ws, size_t ws_size,
                              hipStream_t stream) {
    const int*   zat  = (const int*)  d_in[0];
    const float* pos  = (const float*)d_in[1];
    const float* cell = (const float*)d_in[2];
    const float* coff = (const float*)d_in[3];
    const int*   nbr  = (const int*)  d_in[4];
    const float* mask = (const float*)d_in[5];
    const float* emb  = (const float*)d_in[6];
    const float* fw1  = (const float*)d_in[7];
    const float* fb1  = (const float*)d_in[8];
    const float* fw2  = (const float*)d_in[9];
    const float* fb2  = (const float*)d_in[10];
    const float* in2f = (const float*)d_in[11];
    const float* f2w  = (const float*)d_in[12];
    const float* f2b  = (const float*)d_in[13];
    const float* dw   = (const float*)d_in[14];
    const float* db   = (const float*)d_in[15];

    float* x = (float*)d_out;                      // x lives in d_out
    unsigned* codes = (unsigned*)d_ws;             // B*A*N u32         (2 MB)
    __half* Tb = (__half*)(codes + BB*AA*NN);      // 3*KT*FF half      (1.5 MB)
    __half* yA = Tb + 3*KT*FF;                     // B*A*F half        (2 MB)
    __half* yB = yA + BB*AA*FF;                    // B*A*F half        (2 MB)
    short*  Wp = (short*)(yB + BB*AA*FF);          // 8*16384 bf16      (256 KB)

    k_pre  <<<BB*AA*NN/256, 256, 0, stream>>>(pos, cell, coff, nbr, mask, codes);
    k_table<<<3*KT, 128, 0, stream>>>(fw1, fb1, fw2, fb2, Tb);
    k_packW<<<8*16384/256, 256, 0, stream>>>(f2w, dw, in2f, Wp);
    k_first<<<BB*AA/8, 512, 0, stream>>>(zat, emb, in2f, x, yA);

    k_layerM<<<BB*AA/16, 512, 0, stream>>>(codes, Tb,           yA,
                                           Wp,           f2b,        Wp + 3*16384, db,
                                           Wp + 6*16384, x, yB);
    k_layerM<<<BB*AA/16, 512, 0, stream>>>(codes, Tb + KT*FF,   yB,
                                           Wp + 1*16384, f2b + FF,   Wp + 4*16384, db + FF,
                                           Wp + 7*16384, x, yA);
    k_layerM<<<BB*AA/16, 512, 0, stream>>>(codes, Tb + 2*KT*FF, yA,
                                           Wp + 2*16384, f2b + 2*FF, Wp + 5*16384, db + 2*FF,
                                           nullptr, x, nullptr);
}

// Round 6
// 83.024 us; speedup vs baseline: 16.0619x; 1.3920x over previous
//
#include <hip/hip_runtime.h>
#include <hip/hip_fp16.h>
#include <math.h>

#define BB 8
#define AA 1024
#define NN 64
#define FF 128
#define NG 25

#define WIDTH 0.2083333333f     /* 5/24 */
#define COEF  (-0.5f/(WIDTH*WIDTH))
#define PI_F  3.14159265358979f
#define CUTOFF 5.0f

#define KT 2048
#define HT (CUTOFF/(KT-1))
#define INVH ((float)(KT-1)/CUTOFF)

#define STR 132   /* LDS bf16 row stride (264 B) — verified conflict-free */

typedef __attribute__((ext_vector_type(8))) short bf16x8;
typedef __attribute__((ext_vector_type(4))) short bf16x4;
typedef __attribute__((ext_vector_type(4))) float f32x4;

__device__ __forceinline__ float sspf(float x){
    return fmaxf(x, 0.f) + log1pf(expf(-fabsf(x))) - 0.69314718056f;
}
__device__ __forceinline__ short bf16r(float x){
    union { float f; unsigned u; } v; v.f = x;
    unsigned r = v.u + 0x7FFF + ((v.u >> 16) & 1);
    return (short)(r >> 16);
}
__device__ __forceinline__ __half2 h2bc(unsigned u){
    union { unsigned u; __half2 h; } v; v.u = u; return v.h;
}

// ---- geometry precompute: code = nearest-knot index | (neighbor << 16) ----
__global__ void k_pre(const float* __restrict__ pos, const float* __restrict__ cell,
                      const float* __restrict__ coff, const int* __restrict__ nbr,
                      const float* __restrict__ mask,
                      unsigned* __restrict__ codes){
    int flat = blockIdx.x*256 + threadIdx.x;         // < B*A*N
    int b = flat >> 16;
    int a = (flat >> 6) & (AA-1);
    int j = nbr[flat];
    const float* pi = pos + (b*AA + a)*3;
    const float* pj = pos + (b*AA + j)*3;
    const float* co = coff + (size_t)flat*3;
    const float* cl = cell + b*9;
    float ox = co[0]*cl[0] + co[1]*cl[3] + co[2]*cl[6];
    float oy = co[0]*cl[1] + co[1]*cl[4] + co[2]*cl[7];
    float oz = co[0]*cl[2] + co[1]*cl[5] + co[2]*cl[8];
    float vx = pj[0]-pi[0]+ox, vy = pj[1]-pi[1]+oy, vz = pj[2]-pi[2]+oz;
    float d2 = vx*vx + vy*vy + vz*vz;
    float m  = mask[flat];
    float r  = sqrtf(m > 0.f ? d2 : 1.0f) * m;
    int iv;
    if(m > 0.f && r < CUTOFF){
        iv = (int)(r*INVH + 0.5f);
        if(iv > KT-1) iv = KT-1;
    } else {
        iv = KT-1;                 // T[KT-1] = 0 (C(cutoff)=0)
    }
    codes[flat] = (unsigned)iv | ((unsigned)j << 16);
}

// ---- pack 12 weight matrices into bf16 MFMA B-fragment order ----
// id 0..2: f2out_w[l]; 3..5: dense_w[l]; 6..8: in2f_w[l]; 9..11: fw2[l]
// out[id][ks][nt][lane][i] = W[32ks+8(lane>>4)+i][16nt+(lane&15)]
__global__ void k_packW(const float* __restrict__ f2w, const float* __restrict__ dw,
                        const float* __restrict__ in2f, const float* __restrict__ fw2,
                        short* __restrict__ out){
    int idx = blockIdx.x*256 + threadIdx.x;          // < 12*16384
    int id = idx >> 14, rem = idx & 16383;
    int ks = rem >> 12, nt = (rem >> 9) & 7, lane = (rem >> 3) & 63, i = rem & 7;
    int k = 32*ks + 8*(lane >> 4) + i;
    int f = 16*nt + (lane & 15);
    const float* src = (id < 3) ? f2w + id*16384
                     : (id < 6) ? dw   + (id-3)*16384
                     : (id < 9) ? in2f + (id-6)*16384
                                : fw2  + (id-9)*16384;
    out[idx] = bf16r(src[k*FF + f]);
}

// ---- filter table via MFMA: 16 knots / block, 512 threads ----
__global__ __launch_bounds__(512) void k_tableM(const float* __restrict__ fw1,
                                                const float* __restrict__ fb1,
                                                const float* __restrict__ fb2,
                                                const short* __restrict__ w2pack,
                                                __half* __restrict__ T){
    __shared__ float s_w1[NG*FF];
    __shared__ float s_g[16*28];
    __shared__ short s_a[16*STR];

    int tid = threadIdx.x, wv = tid >> 6, lane = tid & 63;
    int m = lane & 15, q = lane >> 4;
    int l = blockIdx.x >> 7;           // 128 blocks per layer
    int kb = blockIdx.x & 127;         // knot block: knots 16*kb .. 16*kb+15

    // prefetch fw2 fragments for this wave's 16-column stripe
    const bf16x8* w2v = (const bf16x8*)(w2pack + l*16384);
    bf16x8 wf[4];
    #pragma unroll
    for(int ks = 0; ks < 4; ks++) wf[ks] = w2v[(ks*8 + wv)*64 + lane];

    for(int i = tid; i < NG*FF; i += 512) s_w1[i] = fw1[l*NG*FF + i];
    for(int i = tid; i < 16*NG; i += 512){
        int kn = i/25, g = i - 25*kn;
        float d = (16*kb + kn)*HT - g*WIDTH;
        s_g[kn*28 + g] = expf(COEF*d*d);
    }
    __syncthreads();

    // H[kn][f] = ssp(sum_g s_g * fw1 + fb1)
    {
        int f = tid & (FF-1), g4 = tid >> 7;
        float b1v = fb1[l*FF + f];
        #pragma unroll
        for(int i = 0; i < 4; i++){
            int kn = g4 + 4*i;
            float z = b1v;
            for(int g = 0; g < NG; g++)
                z = fmaf(s_g[kn*28 + g], s_w1[g*FF + f], z);
            s_a[kn*STR + f] = bf16r(sspf(z));
        }
    }
    __syncthreads();

    // W = H @ fw2 + fb2, then * C(r); write fp16
    int col = 16*wv + m;
    float b2 = fb2[l*FF + col];
    f32x4 acc = {b2, b2, b2, b2};
    #pragma unroll
    for(int ks = 0; ks < 4; ks++){
        const short* ap = s_a + m*STR + 32*ks + 8*q;
        bf16x4 lo = *(const bf16x4*)ap;
        bf16x4 hi = *(const bf16x4*)(ap + 4);
        bf16x8 af;
        af[0]=lo[0]; af[1]=lo[1]; af[2]=lo[2]; af[3]=lo[3];
        af[4]=hi[0]; af[5]=hi[1]; af[6]=hi[2]; af[7]=hi[3];
        acc = __builtin_amdgcn_mfma_f32_16x16x32_bf16(af, wf[ks], acc, 0, 0, 0);
    }
    #pragma unroll
    for(int j = 0; j < 4; j++){
        int kn = 16*kb + 4*q + j;
        float r = kn*HT;
        float C = (r < CUTOFF) ? 0.5f*(cosf(r*(PI_F/CUTOFF)) + 1.0f) : 0.f;
        T[(l*KT + kn)*FF + col] = __float2half(acc[j]*C);
    }
}

// ---- x0 = embed[z] (fp32 out); y0 = x0 @ in2f[0] via MFMA (fp16 out) ----
__global__ __launch_bounds__(512) void k_firstM(const int* __restrict__ z,
                                                const float* __restrict__ emb,
                                                const short* __restrict__ wpack,
                                                float* __restrict__ x,
                                                __half* __restrict__ y){
    __shared__ short s_a[16*STR];
    int tid = threadIdx.x, wv = tid >> 6, lane = tid & 63;
    int m = lane & 15, q = lane >> 4;
    int row0 = blockIdx.x*16;

    const bf16x8* wverts = (const bf16x8*)wpack;
    bf16x8 wf[4];
    #pragma unroll
    for(int ks = 0; ks < 4; ks++) wf[ks] = wverts[(ks*8 + wv)*64 + lane];

    for(int i = tid; i < 16*FF; i += 512){
        int rr = i >> 7, f = i & (FF-1);
        float v = emb[z[row0+rr]*FF + f];
        x[(row0+rr)*FF + f] = v;
        s_a[rr*STR + f] = bf16r(v);
    }
    __syncthreads();

    int col = 16*wv + m;
    f32x4 acc = {0.f,0.f,0.f,0.f};
    #pragma unroll
    for(int ks = 0; ks < 4; ks++){
        const short* ap = s_a + m*STR + 32*ks + 8*q;
        bf16x4 lo = *(const bf16x4*)ap;
        bf16x4 hi = *(const bf16x4*)(ap + 4);
        bf16x8 af;
        af[0]=lo[0]; af[1]=lo[1]; af[2]=lo[2]; af[3]=lo[3];
        af[4]=hi[0]; af[5]=hi[1]; af[6]=hi[2]; af[7]=hi[3];
        acc = __builtin_amdgcn_mfma_f32_16x16x32_bf16(af, wf[ks], acc, 0, 0, 0);
    }
    #pragma unroll
    for(int j = 0; j < 4; j++)
        y[(row0 + 4*q + j)*FF + col] = __float2half(acc[j]);
}

// ---- fused layer: conv (uint4 table-gather) + 3 MFMA GEMMs; 16 atoms / 8 waves ----
__global__ __launch_bounds__(512) void k_layerM(const unsigned* __restrict__ codes,
                                                const __half* __restrict__ Tl,
                                                const __half* __restrict__ yin,
                                                const short* __restrict__ w1p,
                                                const float* __restrict__ f2b,
                                                const short* __restrict__ w2p,
                                                const float* __restrict__ db,
                                                const short* __restrict__ w3p,
                                                float* __restrict__ x,
                                                __half* __restrict__ ynext){
    __shared__ unsigned s_code[16*NN];
    __shared__ short s_a[16*STR];
    __shared__ short s_t[16*STR];

    int tid = threadIdx.x, wv = tid >> 6, lane = tid & 63;
    int m = lane & 15, q = lane >> 4;
    int row0 = blockIdx.x*16, b = blockIdx.x >> 6;
    int col = 16*wv + m;

    // ---- prefetch: weight fragments, biases, residual (latency hides under conv) ----
    const bf16x8* w1v = (const bf16x8*)w1p;
    const bf16x8* w2v = (const bf16x8*)w2p;
    const bf16x8* w3v = (const bf16x8*)w3p;
    bf16x8 wf1[4], wf2[4], wf3[4];
    #pragma unroll
    for(int ks = 0; ks < 4; ks++){
        wf1[ks] = w1v[(ks*8 + wv)*64 + lane];
        wf2[ks] = w2v[(ks*8 + wv)*64 + lane];
    }
    if(w3p){
        #pragma unroll
        for(int ks = 0; ks < 4; ks++) wf3[ks] = w3v[(ks*8 + wv)*64 + lane];
    }
    float bias1 = f2b[col], bias2 = db[col];
    float xr[4];
    #pragma unroll
    for(int j = 0; j < 4; j++) xr[j] = x[(row0 + 4*q + j)*FF + col];

    *(uint2*)&s_code[2*tid] = *(const uint2*)&codes[row0*NN + 2*tid];
    __syncthreads();

    // ---- conv: wave handles atoms 2wv,2wv+1; quarter-wave = 1 neighbor, 16B/lane ----
    int qf = lane >> 4, fl = lane & 15, f8 = 8*fl;
    const __half* yb = yin + ((size_t)b*AA << 7) + f8;
    const __half* tb = Tl + f8;
    int a0 = 2*wv, a1 = 2*wv + 1;
    __half2 hz = __float2half2_rn(0.f);
    __half2 pa[4] = {hz,hz,hz,hz}, pb[4] = {hz,hz,hz,hz};
    float ca[8] = {0,0,0,0,0,0,0,0}, cb[8] = {0,0,0,0,0,0,0,0};
    #pragma unroll 4
    for(int t = 0; t < 16; t++){
        unsigned cda = s_code[a0*NN + 4*t + qf];
        unsigned cdb = s_code[a1*NN + 4*t + qf];
        uint4 tva = *(const uint4*)(tb + ((cda & 0xFFFFu) << 7));
        uint4 yva = *(const uint4*)(yb + ((size_t)(cda >> 16) << 7));
        uint4 tvb = *(const uint4*)(tb + ((cdb & 0xFFFFu) << 7));
        uint4 yvb = *(const uint4*)(yb + ((size_t)(cdb >> 16) << 7));
        pa[0] = __hfma2(h2bc(tva.x), h2bc(yva.x), pa[0]);
        pa[1] = __hfma2(h2bc(tva.y), h2bc(yva.y), pa[1]);
        pa[2] = __hfma2(h2bc(tva.z), h2bc(yva.z), pa[2]);
        pa[3] = __hfma2(h2bc(tva.w), h2bc(yva.w), pa[3]);
        pb[0] = __hfma2(h2bc(tvb.x), h2bc(yvb.x), pb[0]);
        pb[1] = __hfma2(h2bc(tvb.y), h2bc(yvb.y), pb[1]);
        pb[2] = __hfma2(h2bc(tvb.z), h2bc(yvb.z), pb[2]);
        pb[3] = __hfma2(h2bc(tvb.w), h2bc(yvb.w), pb[3]);
        if((t & 7) == 7){   // flush fp16 accumulators every 8 neighbors per chain
            #pragma unroll
            for(int c2 = 0; c2 < 4; c2++){
                float2 ua = __half22float2(pa[c2]);
                float2 ub = __half22float2(pb[c2]);
                ca[2*c2]   += ua.x; ca[2*c2+1] += ua.y;
                cb[2*c2]   += ub.x; cb[2*c2+1] += ub.y;
                pa[c2] = hz; pb[c2] = hz;
            }
        }
    }
    #pragma unroll
    for(int i = 0; i < 8; i++){
        ca[i] += __shfl_xor(ca[i], 16);
        ca[i] += __shfl_xor(ca[i], 32);
        cb[i] += __shfl_xor(cb[i], 16);
        cb[i] += __shfl_xor(cb[i], 32);
    }
    if(qf == 0){
        unsigned w0 = (unsigned short)bf16r(ca[0]) | ((unsigned)(unsigned short)bf16r(ca[1]) << 16);
        unsigned w1 = (unsigned short)bf16r(ca[2]) | ((unsigned)(unsigned short)bf16r(ca[3]) << 16);
        unsigned w2 = (unsigned short)bf16r(ca[4]) | ((unsigned)(unsigned short)bf16r(ca[5]) << 16);
        unsigned w3 = (unsigned short)bf16r(ca[6]) | ((unsigned)(unsigned short)bf16r(ca[7]) << 16);
        uint2 u01 = {w0, w1}, u23 = {w2, w3};
        *(uint2*)&s_a[a0*STR + f8]     = u01;
        *(uint2*)&s_a[a0*STR + f8 + 4] = u23;
        unsigned v0 = (unsigned short)bf16r(cb[0]) | ((unsigned)(unsigned short)bf16r(cb[1]) << 16);
        unsigned v1 = (unsigned short)bf16r(cb[2]) | ((unsigned)(unsigned short)bf16r(cb[3]) << 16);
        unsigned v2 = (unsigned short)bf16r(cb[4]) | ((unsigned)(unsigned short)bf16r(cb[5]) << 16);
        unsigned v3 = (unsigned short)bf16r(cb[6]) | ((unsigned)(unsigned short)bf16r(cb[7]) << 16);
        uint2 s01 = {v0, v1}, s23 = {v2, v3};
        *(uint2*)&s_a[a1*STR + f8]     = s01;
        *(uint2*)&s_a[a1*STR + f8 + 4] = s23;
    }
    __syncthreads();

    // ---- GEMM1: t = ssp(agg @ f2w + f2b) ----
    f32x4 acc = {bias1, bias1, bias1, bias1};
    #pragma unroll
    for(int ks = 0; ks < 4; ks++){
        const short* ap = s_a + m*STR + 32*ks + 8*q;
        bf16x4 lo = *(const bf16x4*)ap;
        bf16x4 hi = *(const bf16x4*)(ap + 4);
        bf16x8 af;
        af[0]=lo[0]; af[1]=lo[1]; af[2]=lo[2]; af[3]=lo[3];
        af[4]=hi[0]; af[5]=hi[1]; af[6]=hi[2]; af[7]=hi[3];
        acc = __builtin_amdgcn_mfma_f32_16x16x32_bf16(af, wf1[ks], acc, 0, 0, 0);
    }
    #pragma unroll
    for(int j = 0; j < 4; j++)
        s_t[(4*q + j)*STR + col] = bf16r(sspf(acc[j]));
    __syncthreads();

    // ---- GEMM2: v = t @ dw + db ; xnew = x + v ----
    f32x4 a2 = {bias2, bias2, bias2, bias2};
    #pragma unroll
    for(int ks = 0; ks < 4; ks++){
        const short* ap = s_t + m*STR + 32*ks + 8*q;
        bf16x4 lo = *(const bf16x4*)ap;
        bf16x4 hi = *(const bf16x4*)(ap + 4);
        bf16x8 af;
        af[0]=lo[0]; af[1]=lo[1]; af[2]=lo[2]; af[3]=lo[3];
        af[4]=hi[0]; af[5]=hi[1]; af[6]=hi[2]; af[7]=hi[3];
        a2 = __builtin_amdgcn_mfma_f32_16x16x32_bf16(af, wf2[ks], a2, 0, 0, 0);
    }
    float xn[4];
    #pragma unroll
    for(int j = 0; j < 4; j++){
        xn[j] = xr[j] + a2[j];
        x[(row0 + 4*q + j)*FF + col] = xn[j];
    }
    if(w3p){
        // s_a's last reader was GEMM1 (pre-barrier) -> safe to overwrite now
        #pragma unroll
        for(int j = 0; j < 4; j++)
            s_a[(4*q + j)*STR + col] = bf16r(xn[j]);
        __syncthreads();
        // ---- GEMM3: ynext = xnew @ in2f_next (fp16 out) ----
        f32x4 a3 = {0.f, 0.f, 0.f, 0.f};
        #pragma unroll
        for(int ks = 0; ks < 4; ks++){
            const short* ap = s_a + m*STR + 32*ks + 8*q;
            bf16x4 lo = *(const bf16x4*)ap;
            bf16x4 hi = *(const bf16x4*)(ap + 4);
            bf16x8 af;
            af[0]=lo[0]; af[1]=lo[1]; af[2]=lo[2]; af[3]=lo[3];
            af[4]=hi[0]; af[5]=hi[1]; af[6]=hi[2]; af[7]=hi[3];
            a3 = __builtin_amdgcn_mfma_f32_16x16x32_bf16(af, wf3[ks], a3, 0, 0, 0);
        }
        #pragma unroll
        for(int j = 0; j < 4; j++)
            ynext[(row0 + 4*q + j)*FF + col] = __float2half(a3[j]);
    }
}

extern "C" void kernel_launch(void* const* d_in, const int* in_sizes, int n_in,
                              void* d_out, int out_size, void* d_ws, size_t ws_size,
                              hipStream_t stream) {
    const int*   zat  = (const int*)  d_in[0];
    const float* pos  = (const float*)d_in[1];
    const float* cell = (const float*)d_in[2];
    const float* coff = (const float*)d_in[3];
    const int*   nbr  = (const int*)  d_in[4];
    const float* mask = (const float*)d_in[5];
    const float* emb  = (const float*)d_in[6];
    const float* fw1  = (const float*)d_in[7];
    const float* fb1  = (const float*)d_in[8];
    const float* fw2  = (const float*)d_in[9];
    const float* fb2  = (const float*)d_in[10];
    const float* in2f = (const float*)d_in[11];
    const float* f2w  = (const float*)d_in[12];
    const float* f2b  = (const float*)d_in[13];
    const float* dw   = (const float*)d_in[14];
    const float* db   = (const float*)d_in[15];

    float* x = (float*)d_out;                      // x lives in d_out
    unsigned* codes = (unsigned*)d_ws;             // B*A*N u32         (2 MB)
    __half* Tb = (__half*)(codes + BB*AA*NN);      // 3*KT*FF half      (1.5 MB)
    __half* yA = Tb + 3*KT*FF;                     // B*A*F half        (2 MB)
    __half* yB = yA + BB*AA*FF;                    // B*A*F half        (2 MB)
    short*  Wp = (short*)(yB + BB*AA*FF);          // 12*16384 bf16     (384 KB)

    k_pre   <<<BB*AA*NN/256, 256, 0, stream>>>(pos, cell, coff, nbr, mask, codes);
    k_packW <<<12*16384/256, 256, 0, stream>>>(f2w, dw, in2f, fw2, Wp);
    k_tableM<<<3*KT/16, 512, 0, stream>>>(fw1, fb1, fb2, Wp + 9*16384, Tb);
    k_firstM<<<BB*AA/16, 512, 0, stream>>>(zat, emb, Wp + 6*16384, x, yA);

    k_layerM<<<BB*AA/16, 512, 0, stream>>>(codes, Tb,           yA,
                                           Wp + 0*16384, f2b,        Wp + 3*16384, db,
                                           Wp + 7*16384, x, yB);
    k_layerM<<<BB*AA/16, 512, 0, stream>>>(codes, Tb + KT*FF,   yB,
                                           Wp + 1*16384, f2b + FF,   Wp + 4*16384, db + FF,
                                           Wp + 8*16384, x, yA);
    k_layerM<<<BB*AA/16, 512, 0, stream>>>(codes, Tb + 2*KT*FF, yA,
                                           Wp + 2*16384, f2b + 2*FF, Wp + 5*16384, db + 2*FF,
                                           nullptr, x, nullptr);
}

// Round 7
// 72.294 us; speedup vs baseline: 18.4459x; 1.1484x over previous
//
#include <hip/hip_runtime.h>
#include <hip/hip_fp16.h>
#include <math.h>

#define BB 8
#define AA 1024
#define NN 64
#define FF 128
#define NG 25

#define WIDTH 0.2083333333f     /* 5/24 */
#define COEF  (-0.5f/(WIDTH*WIDTH))
#define PI_F  3.14159265358979f
#define CUTOFF 5.0f

#define KT 2048
#define HT (CUTOFF/(KT-1))
#define INVH ((float)(KT-1)/CUTOFF)

#define STR 132   /* LDS bf16 row stride (264 B) — verified conflict-free */

typedef __attribute__((ext_vector_type(8))) short bf16x8;
typedef __attribute__((ext_vector_type(4))) short bf16x4;
typedef __attribute__((ext_vector_type(4))) float f32x4;

__device__ __forceinline__ float sspf(float x){
    return fmaxf(x, 0.f) + log1pf(expf(-fabsf(x))) - 0.69314718056f;
}
__device__ __forceinline__ short bf16r(float x){
    union { float f; unsigned u; } v; v.f = x;
    unsigned r = v.u + 0x7FFF + ((v.u >> 16) & 1);
    return (short)(r >> 16);
}
__device__ __forceinline__ __half2 h2bc(unsigned u){
    union { unsigned u; __half2 h; } v; v.u = u; return v.h;
}

// ---- prolog A: geometry codes (XCD-swizzled) + weight packing ----
// blocks [0,2048): k_pre work, logical lb = (p&7)*256 + (p>>3)  (batch -> XCD pin)
// blocks [2048,2816): pack 12 weight matrices into MFMA B-fragment order
__global__ __launch_bounds__(256) void k_prolog(const float* __restrict__ pos,
                        const float* __restrict__ cell,
                        const float* __restrict__ coff, const int* __restrict__ nbr,
                        const float* __restrict__ mask, unsigned* __restrict__ codes,
                        const float* __restrict__ f2w, const float* __restrict__ dw,
                        const float* __restrict__ in2f, const float* __restrict__ fw2,
                        short* __restrict__ out){
    int p = blockIdx.x;
    if(p < 2048){
        int lb = (p & 7)*256 + (p >> 3);
        int flat = lb*256 + threadIdx.x;             // < B*A*N
        int b = flat >> 16;
        int a = (flat >> 6) & (AA-1);
        int j = nbr[flat];
        const float* pi = pos + (b*AA + a)*3;
        const float* pj = pos + (b*AA + j)*3;
        const float* co = coff + (size_t)flat*3;
        const float* cl = cell + b*9;
        float ox = co[0]*cl[0] + co[1]*cl[3] + co[2]*cl[6];
        float oy = co[0]*cl[1] + co[1]*cl[4] + co[2]*cl[7];
        float oz = co[0]*cl[2] + co[1]*cl[5] + co[2]*cl[8];
        float vx = pj[0]-pi[0]+ox, vy = pj[1]-pi[1]+oy, vz = pj[2]-pi[2]+oz;
        float d2 = vx*vx + vy*vy + vz*vz;
        float m  = mask[flat];
        float r  = sqrtf(m > 0.f ? d2 : 1.0f) * m;
        int iv;
        if(m > 0.f && r < CUTOFF){
            iv = (int)(r*INVH + 0.5f);
            if(iv > KT-1) iv = KT-1;
        } else {
            iv = KT-1;             // T[KT-1] = 0 (C(cutoff)=0)
        }
        codes[flat] = (unsigned)iv | ((unsigned)j << 16);
    } else {
        // out[id][ks][nt][lane][i] = W[32ks+8(lane>>4)+i][16nt+(lane&15)]
        int idx = (p - 2048)*256 + threadIdx.x;      // < 12*16384
        int id = idx >> 14, rem = idx & 16383;
        int ks = rem >> 12, nt = (rem >> 9) & 7, lane = (rem >> 3) & 63, i = rem & 7;
        int k = 32*ks + 8*(lane >> 4) + i;
        int f = 16*nt + (lane & 15);
        const float* src = (id < 3) ? f2w + id*16384
                         : (id < 6) ? dw   + (id-3)*16384
                         : (id < 9) ? in2f + (id-6)*16384
                                    : fw2  + (id-9)*16384;
        out[idx] = bf16r(src[k*FF + f]);
    }
}

// ---- prolog B: filter table (blocks [0,384)) + embed/in2f0 (blocks [384,896)) ----
__global__ __launch_bounds__(512) void k_tf(const float* __restrict__ fw1,
                                            const float* __restrict__ fb1,
                                            const float* __restrict__ fb2,
                                            const short* __restrict__ Wp,
                                            __half* __restrict__ T,
                                            const int* __restrict__ z,
                                            const float* __restrict__ emb,
                                            float* __restrict__ x,
                                            __half* __restrict__ y){
    __shared__ __align__(16) char smem[NG*FF*4 + 16*28*4 + 16*STR*2];
    float* s_w1 = (float*)smem;                              // NG*FF
    float* s_g  = (float*)(smem + NG*FF*4);                  // 16*28
    short* s_a  = (short*)(smem + NG*FF*4 + 16*28*4);        // 16*STR

    int tid = threadIdx.x, wv = tid >> 6, lane = tid & 63;
    int m = lane & 15, q = lane >> 4;
    int col = 16*wv + m;

    if(blockIdx.x < 384){
        int l = blockIdx.x / 128;          // layer
        int kb = blockIdx.x & 127;         // knots 16*kb .. 16*kb+15
        const bf16x8* w2v = (const bf16x8*)(Wp + (9 + l)*16384);
        bf16x8 wf[4];
        #pragma unroll
        for(int ks = 0; ks < 4; ks++) wf[ks] = w2v[(ks*8 + wv)*64 + lane];

        for(int i = tid; i < NG*FF; i += 512) s_w1[i] = fw1[l*NG*FF + i];
        for(int i = tid; i < 16*NG; i += 512){
            int kn = i/25, g = i - 25*kn;
            float d = (16*kb + kn)*HT - g*WIDTH;
            s_g[kn*28 + g] = expf(COEF*d*d);
        }
        __syncthreads();
        {
            int f = tid & (FF-1), g4 = tid >> 7;
            float b1v = fb1[l*FF + f];
            #pragma unroll
            for(int i = 0; i < 4; i++){
                int kn = g4 + 4*i;
                float zz = b1v;
                for(int g = 0; g < NG; g++)
                    zz = fmaf(s_g[kn*28 + g], s_w1[g*FF + f], zz);
                s_a[kn*STR + f] = bf16r(sspf(zz));
            }
        }
        __syncthreads();
        float b2 = fb2[l*FF + col];
        f32x4 acc = {b2, b2, b2, b2};
        #pragma unroll
        for(int ks = 0; ks < 4; ks++){
            const short* ap = s_a + m*STR + 32*ks + 8*q;
            bf16x4 lo = *(const bf16x4*)ap;
            bf16x4 hi = *(const bf16x4*)(ap + 4);
            bf16x8 af;
            af[0]=lo[0]; af[1]=lo[1]; af[2]=lo[2]; af[3]=lo[3];
            af[4]=hi[0]; af[5]=hi[1]; af[6]=hi[2]; af[7]=hi[3];
            acc = __builtin_amdgcn_mfma_f32_16x16x32_bf16(af, wf[ks], acc, 0, 0, 0);
        }
        #pragma unroll
        for(int j = 0; j < 4; j++){
            int kn = 16*kb + 4*q + j;
            float r = kn*HT;
            float C = (r < CUTOFF) ? 0.5f*(cosf(r*(PI_F/CUTOFF)) + 1.0f) : 0.f;
            T[(l*KT + kn)*FF + col] = __float2half(acc[j]*C);
        }
    } else {
        int pp = blockIdx.x - 384;                 // 512 blocks, XCD-swizzled
        int row0 = ((pp & 7)*64 + (pp >> 3))*16;
        const bf16x8* wverts = (const bf16x8*)(Wp + 6*16384);
        bf16x8 wf[4];
        #pragma unroll
        for(int ks = 0; ks < 4; ks++) wf[ks] = wverts[(ks*8 + wv)*64 + lane];

        for(int i = tid; i < 16*FF; i += 512){
            int rr = i >> 7, f = i & (FF-1);
            float v = emb[z[row0+rr]*FF + f];
            x[(row0+rr)*FF + f] = v;
            s_a[rr*STR + f] = bf16r(v);
        }
        __syncthreads();
        f32x4 acc = {0.f,0.f,0.f,0.f};
        #pragma unroll
        for(int ks = 0; ks < 4; ks++){
            const short* ap = s_a + m*STR + 32*ks + 8*q;
            bf16x4 lo = *(const bf16x4*)ap;
            bf16x4 hi = *(const bf16x4*)(ap + 4);
            bf16x8 af;
            af[0]=lo[0]; af[1]=lo[1]; af[2]=lo[2]; af[3]=lo[3];
            af[4]=hi[0]; af[5]=hi[1]; af[6]=hi[2]; af[7]=hi[3];
            acc = __builtin_amdgcn_mfma_f32_16x16x32_bf16(af, wf[ks], acc, 0, 0, 0);
        }
        #pragma unroll
        for(int j = 0; j < 4; j++)
            y[(row0 + 4*q + j)*FF + col] = __float2half(acc[j]);
    }
}

// ---- fused layer: conv (uint4 table-gather) + 3 MFMA GEMMs; 16 atoms / 8 waves ----
// XCD swizzle: physical p -> batch b = p&7 (pins batch to XCD), atom-block = p>>3
__global__ __launch_bounds__(512) void k_layerM(const unsigned* __restrict__ codes,
                                                const __half* __restrict__ Tl,
                                                const __half* __restrict__ yin,
                                                const short* __restrict__ w1p,
                                                const float* __restrict__ f2b,
                                                const short* __restrict__ w2p,
                                                const float* __restrict__ db,
                                                const short* __restrict__ w3p,
                                                float* __restrict__ x,
                                                __half* __restrict__ ynext){
    __shared__ unsigned s_code[16*NN];
    __shared__ short s_a[16*STR];
    __shared__ short s_t[16*STR];

    int tid = threadIdx.x, wv = tid >> 6, lane = tid & 63;
    int m = lane & 15, q = lane >> 4;
    int p = blockIdx.x;
    int b = p & 7;
    int row0 = (b*64 + (p >> 3))*16;
    int col = 16*wv + m;

    // ---- prefetch: weight fragments, biases, residual (latency hides under conv) ----
    const bf16x8* w1v = (const bf16x8*)w1p;
    const bf16x8* w2v = (const bf16x8*)w2p;
    const bf16x8* w3v = (const bf16x8*)w3p;
    bf16x8 wf1[4], wf2[4], wf3[4];
    #pragma unroll
    for(int ks = 0; ks < 4; ks++){
        wf1[ks] = w1v[(ks*8 + wv)*64 + lane];
        wf2[ks] = w2v[(ks*8 + wv)*64 + lane];
    }
    if(w3p){
        #pragma unroll
        for(int ks = 0; ks < 4; ks++) wf3[ks] = w3v[(ks*8 + wv)*64 + lane];
    }
    float bias1 = f2b[col], bias2 = db[col];
    float xr[4];
    #pragma unroll
    for(int j = 0; j < 4; j++) xr[j] = x[(row0 + 4*q + j)*FF + col];

    *(uint2*)&s_code[2*tid] = *(const uint2*)&codes[row0*NN + 2*tid];
    __syncthreads();

    // ---- conv: wave handles atoms 2wv,2wv+1; quarter-wave = 1 neighbor, 16B/lane ----
    int qf = lane >> 4, fl = lane & 15, f8 = 8*fl;
    const __half* yb = yin + ((size_t)b*AA << 7) + f8;
    const __half* tb = Tl + f8;
    int a0 = 2*wv, a1 = 2*wv + 1;
    __half2 hz = __float2half2_rn(0.f);
    __half2 pa[4] = {hz,hz,hz,hz}, pb[4] = {hz,hz,hz,hz};
    float ca[8] = {0,0,0,0,0,0,0,0}, cb[8] = {0,0,0,0,0,0,0,0};
    #pragma unroll 4
    for(int t = 0; t < 16; t++){
        unsigned cda = s_code[a0*NN + 4*t + qf];
        unsigned cdb = s_code[a1*NN + 4*t + qf];
        uint4 tva = *(const uint4*)(tb + ((cda & 0xFFFFu) << 7));
        uint4 yva = *(const uint4*)(yb + ((size_t)(cda >> 16) << 7));
        uint4 tvb = *(const uint4*)(tb + ((cdb & 0xFFFFu) << 7));
        uint4 yvb = *(const uint4*)(yb + ((size_t)(cdb >> 16) << 7));
        pa[0] = __hfma2(h2bc(tva.x), h2bc(yva.x), pa[0]);
        pa[1] = __hfma2(h2bc(tva.y), h2bc(yva.y), pa[1]);
        pa[2] = __hfma2(h2bc(tva.z), h2bc(yva.z), pa[2]);
        pa[3] = __hfma2(h2bc(tva.w), h2bc(yva.w), pa[3]);
        pb[0] = __hfma2(h2bc(tvb.x), h2bc(yvb.x), pb[0]);
        pb[1] = __hfma2(h2bc(tvb.y), h2bc(yvb.y), pb[1]);
        pb[2] = __hfma2(h2bc(tvb.z), h2bc(yvb.z), pb[2]);
        pb[3] = __hfma2(h2bc(tvb.w), h2bc(yvb.w), pb[3]);
        if((t & 7) == 7){   // flush fp16 accumulators every 8 neighbors per chain
            #pragma unroll
            for(int c2 = 0; c2 < 4; c2++){
                float2 ua = __half22float2(pa[c2]);
                float2 ub = __half22float2(pb[c2]);
                ca[2*c2]   += ua.x; ca[2*c2+1] += ua.y;
                cb[2*c2]   += ub.x; cb[2*c2+1] += ub.y;
                pa[c2] = hz; pb[c2] = hz;
            }
        }
    }
    #pragma unroll
    for(int i = 0; i < 8; i++){
        ca[i] += __shfl_xor(ca[i], 16);
        ca[i] += __shfl_xor(ca[i], 32);
        cb[i] += __shfl_xor(cb[i], 16);
        cb[i] += __shfl_xor(cb[i], 32);
    }
    if(qf == 0){
        unsigned w0 = (unsigned short)bf16r(ca[0]) | ((unsigned)(unsigned short)bf16r(ca[1]) << 16);
        unsigned w1 = (unsigned short)bf16r(ca[2]) | ((unsigned)(unsigned short)bf16r(ca[3]) << 16);
        unsigned w2 = (unsigned short)bf16r(ca[4]) | ((unsigned)(unsigned short)bf16r(ca[5]) << 16);
        unsigned w3 = (unsigned short)bf16r(ca[6]) | ((unsigned)(unsigned short)bf16r(ca[7]) << 16);
        uint2 u01 = {w0, w1}, u23 = {w2, w3};
        *(uint2*)&s_a[a0*STR + f8]     = u01;
        *(uint2*)&s_a[a0*STR + f8 + 4] = u23;
        unsigned v0 = (unsigned short)bf16r(cb[0]) | ((unsigned)(unsigned short)bf16r(cb[1]) << 16);
        unsigned v1 = (unsigned short)bf16r(cb[2]) | ((unsigned)(unsigned short)bf16r(cb[3]) << 16);
        unsigned v2 = (unsigned short)bf16r(cb[4]) | ((unsigned)(unsigned short)bf16r(cb[5]) << 16);
        unsigned v3 = (unsigned short)bf16r(cb[6]) | ((unsigned)(unsigned short)bf16r(cb[7]) << 16);
        uint2 s01 = {v0, v1}, s23 = {v2, v3};
        *(uint2*)&s_a[a1*STR + f8]     = s01;
        *(uint2*)&s_a[a1*STR + f8 + 4] = s23;
    }
    __syncthreads();

    // ---- GEMM1: t = ssp(agg @ f2w + f2b) ----
    f32x4 acc = {bias1, bias1, bias1, bias1};
    #pragma unroll
    for(int ks = 0; ks < 4; ks++){
        const short* ap = s_a + m*STR + 32*ks + 8*q;
        bf16x4 lo = *(const bf16x4*)ap;
        bf16x4 hi = *(const bf16x4*)(ap + 4);
        bf16x8 af;
        af[0]=lo[0]; af[1]=lo[1]; af[2]=lo[2]; af[3]=lo[3];
        af[4]=hi[0]; af[5]=hi[1]; af[6]=hi[2]; af[7]=hi[3];
        acc = __builtin_amdgcn_mfma_f32_16x16x32_bf16(af, wf1[ks], acc, 0, 0, 0);
    }
    #pragma unroll
    for(int j = 0; j < 4; j++)
        s_t[(4*q + j)*STR + col] = bf16r(sspf(acc[j]));
    __syncthreads();

    // ---- GEMM2: v = t @ dw + db ; xnew = x + v ----
    f32x4 a2 = {bias2, bias2, bias2, bias2};
    #pragma unroll
    for(int ks = 0; ks < 4; ks++){
        const short* ap = s_t + m*STR + 32*ks + 8*q;
        bf16x4 lo = *(const bf16x4*)ap;
        bf16x4 hi = *(const bf16x4*)(ap + 4);
        bf16x8 af;
        af[0]=lo[0]; af[1]=lo[1]; af[2]=lo[2]; af[3]=lo[3];
        af[4]=hi[0]; af[5]=hi[1]; af[6]=hi[2]; af[7]=hi[3];
        a2 = __builtin_amdgcn_mfma_f32_16x16x32_bf16(af, wf2[ks], a2, 0, 0, 0);
    }
    float xn[4];
    #pragma unroll
    for(int j = 0; j < 4; j++){
        xn[j] = xr[j] + a2[j];
        x[(row0 + 4*q + j)*FF + col] = xn[j];
    }
    if(w3p){
        // s_a's last reader was GEMM1 (pre-barrier) -> safe to overwrite now
        #pragma unroll
        for(int j = 0; j < 4; j++)
            s_a[(4*q + j)*STR + col] = bf16r(xn[j]);
        __syncthreads();
        // ---- GEMM3: ynext = xnew @ in2f_next (fp16 out) ----
        f32x4 a3 = {0.f, 0.f, 0.f, 0.f};
        #pragma unroll
        for(int ks = 0; ks < 4; ks++){
            const short* ap = s_a + m*STR + 32*ks + 8*q;
            bf16x4 lo = *(const bf16x4*)ap;
            bf16x4 hi = *(const bf16x4*)(ap + 4);
            bf16x8 af;
            af[0]=lo[0]; af[1]=lo[1]; af[2]=lo[2]; af[3]=lo[3];
            af[4]=hi[0]; af[5]=hi[1]; af[6]=hi[2]; af[7]=hi[3];
            a3 = __builtin_amdgcn_mfma_f32_16x16x32_bf16(af, wf3[ks], a3, 0, 0, 0);
        }
        #pragma unroll
        for(int j = 0; j < 4; j++)
            ynext[(row0 + 4*q + j)*FF + col] = __float2half(a3[j]);
    }
}

extern "C" void kernel_launch(void* const* d_in, const int* in_sizes, int n_in,
                              void* d_out, int out_size, void* d_ws, size_t ws_size,
                              hipStream_t stream) {
    const int*   zat  = (const int*)  d_in[0];
    const float* pos  = (const float*)d_in[1];
    const float* cell = (const float*)d_in[2];
    const float* coff = (const float*)d_in[3];
    const int*   nbr  = (const int*)  d_in[4];
    const float* mask = (const float*)d_in[5];
    const float* emb  = (const float*)d_in[6];
    const float* fw1  = (const float*)d_in[7];
    const float* fb1  = (const float*)d_in[8];
    const float* fw2  = (const float*)d_in[9];
    const float* fb2  = (const float*)d_in[10];
    const float* in2f = (const float*)d_in[11];
    const float* f2w  = (const float*)d_in[12];
    const float* f2b  = (const float*)d_in[13];
    const float* dw   = (const float*)d_in[14];
    const float* db   = (const float*)d_in[15];

    float* x = (float*)d_out;                      // x lives in d_out
    unsigned* codes = (unsigned*)d_ws;             // B*A*N u32         (2 MB)
    __half* Tb = (__half*)(codes + BB*AA*NN);      // 3*KT*FF half      (1.5 MB)
    __half* yA = Tb + 3*KT*FF;                     // B*A*F half        (2 MB)
    __half* yB = yA + BB*AA*FF;                    // B*A*F half        (2 MB)
    short*  Wp = (short*)(yB + BB*AA*FF);          // 12*16384 bf16     (384 KB)

    k_prolog<<<2048 + 12*16384/256, 256, 0, stream>>>(pos, cell, coff, nbr, mask, codes,
                                                      f2w, dw, in2f, fw2, Wp);
    k_tf    <<<384 + BB*AA/16, 512, 0, stream>>>(fw1, fb1, fb2, Wp, Tb, zat, emb, x, yA);

    k_layerM<<<BB*AA/16, 512, 0, stream>>>(codes, Tb,           yA,
                                           Wp + 0*16384, f2b,        Wp + 3*16384, db,
                                           Wp + 7*16384, x, yB);
    k_layerM<<<BB*AA/16, 512, 0, stream>>>(codes, Tb + KT*FF,   yB,
                                           Wp + 1*16384, f2b + FF,   Wp + 4*16384, db + FF,
                                           Wp + 8*16384, x, yA);
    k_layerM<<<BB*AA/16, 512, 0, stream>>>(codes, Tb + 2*KT*FF, yA,
                                           Wp + 2*16384, f2b + 2*FF, Wp + 5*16384, db + 2*FF,
                                           nullptr, x, nullptr);
}

// Round 9
// 66.310 us; speedup vs baseline: 20.1105x; 1.0902x over previous
//
#include <hip/hip_runtime.h>
#include <hip/hip_fp16.h>
#include <math.h>

#define BB 8
#define AA 1024
#define NN 64
#define FF 128
#define NG 25

#define WIDTH 0.2083333333f     /* 5/24 */
#define COEF  (-0.5f/(WIDTH*WIDTH))
#define PI_F  3.14159265358979f
#define CUTOFF 5.0f

#define KT 2048
#define HT (CUTOFF/(KT-1))
#define INVH ((float)(KT-1)/CUTOFF)

#define STR 132   /* LDS bf16 row stride (264 B) — verified conflict-free */

typedef __attribute__((ext_vector_type(8))) short bf16x8;
typedef __attribute__((ext_vector_type(4))) short bf16x4;
typedef __attribute__((ext_vector_type(4))) float f32x4;

__device__ __forceinline__ float sspf(float x){
    return fmaxf(x, 0.f) + log1pf(expf(-fabsf(x))) - 0.69314718056f;
}
__device__ __forceinline__ short bf16r(float x){
    union { float f; unsigned u; } v; v.f = x;
    unsigned r = v.u + 0x7FFF + ((v.u >> 16) & 1);
    return (short)(r >> 16);
}
__device__ __forceinline__ __half2 h2bc(unsigned u){
    union { unsigned u; __half2 h; } v; v.u = u; return v.h;
}

// ---- prolog A: geometry codes (XCD-swizzled) + weight packing ----
__global__ __launch_bounds__(256) void k_prolog(const float* __restrict__ pos,
                        const float* __restrict__ cell,
                        const float* __restrict__ coff, const int* __restrict__ nbr,
                        const float* __restrict__ mask, unsigned* __restrict__ codes,
                        const float* __restrict__ f2w, const float* __restrict__ dw,
                        const float* __restrict__ in2f, const float* __restrict__ fw2,
                        short* __restrict__ out){
    int p = blockIdx.x;
    if(p < 2048){
        int lb = (p & 7)*256 + (p >> 3);
        int flat = lb*256 + threadIdx.x;             // < B*A*N
        int b = flat >> 16;
        int a = (flat >> 6) & (AA-1);
        int j = nbr[flat];
        const float* pi = pos + (b*AA + a)*3;
        const float* pj = pos + (b*AA + j)*3;
        const float* co = coff + (size_t)flat*3;
        const float* cl = cell + b*9;
        float ox = co[0]*cl[0] + co[1]*cl[3] + co[2]*cl[6];
        float oy = co[0]*cl[1] + co[1]*cl[4] + co[2]*cl[7];
        float oz = co[0]*cl[2] + co[1]*cl[5] + co[2]*cl[8];
        float vx = pj[0]-pi[0]+ox, vy = pj[1]-pi[1]+oy, vz = pj[2]-pi[2]+oz;
        float d2 = vx*vx + vy*vy + vz*vz;
        float m  = mask[flat];
        float r  = sqrtf(m > 0.f ? d2 : 1.0f) * m;
        int iv;
        if(m > 0.f && r < CUTOFF){
            iv = (int)(r*INVH + 0.5f);
            if(iv > KT-1) iv = KT-1;
        } else {
            iv = KT-1;             // T[KT-1] = 0 (C(cutoff)=0)
        }
        codes[flat] = (unsigned)iv | ((unsigned)j << 16);
    } else {
        int idx = (p - 2048)*256 + threadIdx.x;      // < 12*16384
        int id = idx >> 14, rem = idx & 16383;
        int ks = rem >> 12, nt = (rem >> 9) & 7, lane = (rem >> 3) & 63, i = rem & 7;
        int k = 32*ks + 8*(lane >> 4) + i;
        int f = 16*nt + (lane & 15);
        const float* src = (id < 3) ? f2w + id*16384
                         : (id < 6) ? dw   + (id-3)*16384
                         : (id < 9) ? in2f + (id-6)*16384
                                    : fw2  + (id-9)*16384;
        out[idx] = bf16r(src[k*FF + f]);
    }
}

// ---- prolog B: filter table (blocks [0,384)) + embed/in2f0 (blocks [384,896)) ----
__global__ __launch_bounds__(512) void k_tf(const float* __restrict__ fw1,
                                            const float* __restrict__ fb1,
                                            const float* __restrict__ fb2,
                                            const short* __restrict__ Wp,
                                            __half* __restrict__ T,
                                            const int* __restrict__ z,
                                            const float* __restrict__ emb,
                                            float* __restrict__ x,
                                            __half* __restrict__ y){
    __shared__ __align__(16) char smem[NG*FF*4 + 16*28*4 + 16*STR*2];
    float* s_w1 = (float*)smem;                              // NG*FF
    float* s_g  = (float*)(smem + NG*FF*4);                  // 16*28
    short* s_a  = (short*)(smem + NG*FF*4 + 16*28*4);        // 16*STR

    int tid = threadIdx.x, wv = tid >> 6, lane = tid & 63;
    int m = lane & 15, q = lane >> 4;
    int col = 16*wv + m;

    if(blockIdx.x < 384){
        int l = blockIdx.x / 128;          // layer
        int kb = blockIdx.x & 127;         // knots 16*kb .. 16*kb+15
        const bf16x8* w2v = (const bf16x8*)(Wp + (9 + l)*16384);
        bf16x8 wf[4];
        #pragma unroll
        for(int ks = 0; ks < 4; ks++) wf[ks] = w2v[(ks*8 + wv)*64 + lane];

        for(int i = tid; i < NG*FF; i += 512) s_w1[i] = fw1[l*NG*FF + i];
        for(int i = tid; i < 16*NG; i += 512){
            int kn = i/25, g = i - 25*kn;
            float d = (16*kb + kn)*HT - g*WIDTH;
            s_g[kn*28 + g] = expf(COEF*d*d);
        }
        __syncthreads();
        {
            int f = tid & (FF-1), g4 = tid >> 7;
            float b1v = fb1[l*FF + f];
            #pragma unroll
            for(int i = 0; i < 4; i++){
                int kn = g4 + 4*i;
                float zz = b1v;
                for(int g = 0; g < NG; g++)
                    zz = fmaf(s_g[kn*28 + g], s_w1[g*FF + f], zz);
                s_a[kn*STR + f] = bf16r(sspf(zz));
            }
        }
        __syncthreads();
        float b2 = fb2[l*FF + col];
        f32x4 acc = {b2, b2, b2, b2};
        #pragma unroll
        for(int ks = 0; ks < 4; ks++){
            const short* ap = s_a + m*STR + 32*ks + 8*q;
            bf16x4 lo = *(const bf16x4*)ap;
            bf16x4 hi = *(const bf16x4*)(ap + 4);
            bf16x8 af;
            af[0]=lo[0]; af[1]=lo[1]; af[2]=lo[2]; af[3]=lo[3];
            af[4]=hi[0]; af[5]=hi[1]; af[6]=hi[2]; af[7]=hi[3];
            acc = __builtin_amdgcn_mfma_f32_16x16x32_bf16(af, wf[ks], acc, 0, 0, 0);
        }
        #pragma unroll
        for(int j = 0; j < 4; j++){
            int kn = 16*kb + 4*q + j;
            float r = kn*HT;
            float C = (r < CUTOFF) ? 0.5f*(cosf(r*(PI_F/CUTOFF)) + 1.0f) : 0.f;
            T[(l*KT + kn)*FF + col] = __float2half(acc[j]*C);
        }
    } else {
        int pp = blockIdx.x - 384;                 // 512 blocks, XCD-swizzled
        int row0 = ((pp & 7)*64 + (pp >> 3))*16;
        const bf16x8* wverts = (const bf16x8*)(Wp + 6*16384);
        bf16x8 wf[4];
        #pragma unroll
        for(int ks = 0; ks < 4; ks++) wf[ks] = wverts[(ks*8 + wv)*64 + lane];

        for(int i = tid; i < 16*FF; i += 512){
            int rr = i >> 7, f = i & (FF-1);
            float v = emb[z[row0+rr]*FF + f];
            x[(row0+rr)*FF + f] = v;
            s_a[rr*STR + f] = bf16r(v);
        }
        __syncthreads();
        f32x4 acc = {0.f,0.f,0.f,0.f};
        #pragma unroll
        for(int ks = 0; ks < 4; ks++){
            const short* ap = s_a + m*STR + 32*ks + 8*q;
            bf16x4 lo = *(const bf16x4*)ap;
            bf16x4 hi = *(const bf16x4*)(ap + 4);
            bf16x8 af;
            af[0]=lo[0]; af[1]=lo[1]; af[2]=lo[2]; af[3]=lo[3];
            af[4]=hi[0]; af[5]=hi[1]; af[6]=hi[2]; af[7]=hi[3];
            acc = __builtin_amdgcn_mfma_f32_16x16x32_bf16(af, wf[ks], acc, 0, 0, 0);
        }
        #pragma unroll
        for(int j = 0; j < 4; j++)
            y[(row0 + 4*q + j)*FF + col] = __float2half(acc[j]);
    }
}

// ---- fused layer: conv + 3 MFMA GEMMs ----
// weights loaded just-before-use via opaque pointers (keeps conv-phase VGPR low);
// fresh register sets per GEMM, no sched fences, no launch_bounds cap (r8 lesson)
__global__ __launch_bounds__(512) void k_layerM(const unsigned* __restrict__ codes,
                                                const __half* __restrict__ Tl,
                                                const __half* __restrict__ yin,
                                                const short* __restrict__ w1p,
                                                const float* __restrict__ f2b,
                                                const short* __restrict__ w2p,
                                                const float* __restrict__ db,
                                                const short* __restrict__ w3p,
                                                float* __restrict__ x,
                                                __half* __restrict__ ynext){
    __shared__ unsigned s_code[16*NN];
    __shared__ short s_a[16*STR];
    __shared__ short s_t[16*STR];

    int tid = threadIdx.x, wv = tid >> 6, lane = tid & 63;
    int m = lane & 15, q = lane >> 4;
    int p = blockIdx.x;
    int b = p & 7;
    int row0 = (b*64 + (p >> 3))*16;
    int col = 16*wv + m;

    float bias1 = f2b[col], bias2 = db[col];
    float xr[4];
    #pragma unroll
    for(int j = 0; j < 4; j++) xr[j] = x[(row0 + 4*q + j)*FF + col];

    *(uint2*)&s_code[2*tid] = *(const uint2*)&codes[row0*NN + 2*tid];
    __syncthreads();

    // ---- conv: wave handles atoms 2wv,2wv+1; quarter-wave = 1 neighbor, 16B/lane ----
    int qf = lane >> 4, fl = lane & 15, f8 = 8*fl;
    const __half* yb = yin + ((size_t)b*AA << 7) + f8;
    const __half* tb = Tl + f8;
    int a0 = 2*wv, a1 = 2*wv + 1;
    __half2 hz = __float2half2_rn(0.f);
    __half2 pa[4] = {hz,hz,hz,hz}, pb[4] = {hz,hz,hz,hz};
    float ca[8] = {0,0,0,0,0,0,0,0}, cb[8] = {0,0,0,0,0,0,0,0};
    #pragma unroll 4
    for(int t = 0; t < 16; t++){
        unsigned cda = s_code[a0*NN + 4*t + qf];
        unsigned cdb = s_code[a1*NN + 4*t + qf];
        uint4 tva = *(const uint4*)(tb + ((cda & 0xFFFFu) << 7));
        uint4 yva = *(const uint4*)(yb + ((size_t)(cda >> 16) << 7));
        uint4 tvb = *(const uint4*)(tb + ((cdb & 0xFFFFu) << 7));
        uint4 yvb = *(const uint4*)(yb + ((size_t)(cdb >> 16) << 7));
        pa[0] = __hfma2(h2bc(tva.x), h2bc(yva.x), pa[0]);
        pa[1] = __hfma2(h2bc(tva.y), h2bc(yva.y), pa[1]);
        pa[2] = __hfma2(h2bc(tva.z), h2bc(yva.z), pa[2]);
        pa[3] = __hfma2(h2bc(tva.w), h2bc(yva.w), pa[3]);
        pb[0] = __hfma2(h2bc(tvb.x), h2bc(yvb.x), pb[0]);
        pb[1] = __hfma2(h2bc(tvb.y), h2bc(yvb.y), pb[1]);
        pb[2] = __hfma2(h2bc(tvb.z), h2bc(yvb.z), pb[2]);
        pb[3] = __hfma2(h2bc(tvb.w), h2bc(yvb.w), pb[3]);
        if((t & 7) == 7){   // flush fp16 accumulators every 8 neighbors per chain
            #pragma unroll
            for(int c2 = 0; c2 < 4; c2++){
                float2 ua = __half22float2(pa[c2]);
                float2 ub = __half22float2(pb[c2]);
                ca[2*c2]   += ua.x; ca[2*c2+1] += ua.y;
                cb[2*c2]   += ub.x; cb[2*c2+1] += ub.y;
                pa[c2] = hz; pb[c2] = hz;
            }
        }
    }
    #pragma unroll
    for(int i = 0; i < 8; i++){
        ca[i] += __shfl_xor(ca[i], 16);
        ca[i] += __shfl_xor(ca[i], 32);
        cb[i] += __shfl_xor(cb[i], 16);
        cb[i] += __shfl_xor(cb[i], 32);
    }
    if(qf == 0){
        unsigned w0 = (unsigned short)bf16r(ca[0]) | ((unsigned)(unsigned short)bf16r(ca[1]) << 16);
        unsigned w1 = (unsigned short)bf16r(ca[2]) | ((unsigned)(unsigned short)bf16r(ca[3]) << 16);
        unsigned w2 = (unsigned short)bf16r(ca[4]) | ((unsigned)(unsigned short)bf16r(ca[5]) << 16);
        unsigned w3 = (unsigned short)bf16r(ca[6]) | ((unsigned)(unsigned short)bf16r(ca[7]) << 16);
        uint2 u01 = {w0, w1}, u23 = {w2, w3};
        *(uint2*)&s_a[a0*STR + f8]     = u01;
        *(uint2*)&s_a[a0*STR + f8 + 4] = u23;
        unsigned v0 = (unsigned short)bf16r(cb[0]) | ((unsigned)(unsigned short)bf16r(cb[1]) << 16);
        unsigned v1 = (unsigned short)bf16r(cb[2]) | ((unsigned)(unsigned short)bf16r(cb[3]) << 16);
        unsigned v2 = (unsigned short)bf16r(cb[4]) | ((unsigned)(unsigned short)bf16r(cb[5]) << 16);
        unsigned v3 = (unsigned short)bf16r(cb[6]) | ((unsigned)(unsigned short)bf16r(cb[7]) << 16);
        uint2 s01 = {v0, v1}, s23 = {v2, v3};
        *(uint2*)&s_a[a1*STR + f8]     = s01;
        *(uint2*)&s_a[a1*STR + f8 + 4] = s23;
    }

    // ---- GEMM1 weights: loaded HERE (not at entry) via opaque pointer ----
    unsigned long long w1o = (unsigned long long)w1p;
    asm volatile("" : "+s"(w1o));                  // value-preserving; blocks hoisting
    bf16x8 wfa[4];
    {
        const bf16x8* w1v = (const bf16x8*)w1o;
        #pragma unroll
        for(int ks = 0; ks < 4; ks++) wfa[ks] = w1v[(ks*8 + wv)*64 + lane];
    }
    __syncthreads();

    // ---- GEMM1: t = ssp(agg @ f2w + f2b) ----
    f32x4 acc = {bias1, bias1, bias1, bias1};
    #pragma unroll
    for(int ks = 0; ks < 4; ks++){
        const short* ap = s_a + m*STR + 32*ks + 8*q;
        bf16x4 lo = *(const bf16x4*)ap;
        bf16x4 hi = *(const bf16x4*)(ap + 4);
        bf16x8 af;
        af[0]=lo[0]; af[1]=lo[1]; af[2]=lo[2]; af[3]=lo[3];
        af[4]=hi[0]; af[5]=hi[1]; af[6]=hi[2]; af[7]=hi[3];
        acc = __builtin_amdgcn_mfma_f32_16x16x32_bf16(af, wfa[ks], acc, 0, 0, 0);
    }

    // ---- GEMM2 weights: fresh set, loaded after GEMM1 ----
    unsigned long long w2o = (unsigned long long)w2p;
    asm volatile("" : "+s"(w2o));
    bf16x8 wfb[4];
    {
        const bf16x8* w2v = (const bf16x8*)w2o;
        #pragma unroll
        for(int ks = 0; ks < 4; ks++) wfb[ks] = w2v[(ks*8 + wv)*64 + lane];
    }

    #pragma unroll
    for(int j = 0; j < 4; j++)
        s_t[(4*q + j)*STR + col] = bf16r(sspf(acc[j]));
    __syncthreads();

    // ---- GEMM2: v = t @ dw + db ; xnew = x + v ----
    f32x4 a2 = {bias2, bias2, bias2, bias2};
    #pragma unroll
    for(int ks = 0; ks < 4; ks++){
        const short* ap = s_t + m*STR + 32*ks + 8*q;
        bf16x4 lo = *(const bf16x4*)ap;
        bf16x4 hi = *(const bf16x4*)(ap + 4);
        bf16x8 af;
        af[0]=lo[0]; af[1]=lo[1]; af[2]=lo[2]; af[3]=lo[3];
        af[4]=hi[0]; af[5]=hi[1]; af[6]=hi[2]; af[7]=hi[3];
        a2 = __builtin_amdgcn_mfma_f32_16x16x32_bf16(af, wfb[ks], a2, 0, 0, 0);
    }

    float xn[4];
    #pragma unroll
    for(int j = 0; j < 4; j++){
        xn[j] = xr[j] + a2[j];
        x[(row0 + 4*q + j)*FF + col] = xn[j];
    }
    if(w3p){
        // ---- GEMM3 weights: fresh set ----
        unsigned long long w3o = (unsigned long long)w3p;
        asm volatile("" : "+s"(w3o));
        bf16x8 wfc[4];
        {
            const bf16x8* w3v = (const bf16x8*)w3o;
            #pragma unroll
            for(int ks = 0; ks < 4; ks++) wfc[ks] = w3v[(ks*8 + wv)*64 + lane];
        }
        // s_a's last reader was GEMM1 (pre-barrier) -> safe to overwrite now
        #pragma unroll
        for(int j = 0; j < 4; j++)
            s_a[(4*q + j)*STR + col] = bf16r(xn[j]);
        __syncthreads();
        // ---- GEMM3: ynext = xnew @ in2f_next (fp16 out) ----
        f32x4 a3 = {0.f, 0.f, 0.f, 0.f};
        #pragma unroll
        for(int ks = 0; ks < 4; ks++){
            const short* ap = s_a + m*STR + 32*ks + 8*q;
            bf16x4 lo = *(const bf16x4*)ap;
            bf16x4 hi = *(const bf16x4*)(ap + 4);
            bf16x8 af;
            af[0]=lo[0]; af[1]=lo[1]; af[2]=lo[2]; af[3]=lo[3];
            af[4]=hi[0]; af[5]=hi[1]; af[6]=hi[2]; af[7]=hi[3];
            a3 = __builtin_amdgcn_mfma_f32_16x16x32_bf16(af, wfc[ks], a3, 0, 0, 0);
        }
        #pragma unroll
        for(int j = 0; j < 4; j++)
            ynext[(row0 + 4*q + j)*FF + col] = __float2half(a3[j]);
    }
}

extern "C" void kernel_launch(void* const* d_in, const int* in_sizes, int n_in,
                              void* d_out, int out_size, void* d_ws, size_t ws_size,
                              hipStream_t stream) {
    const int*   zat  = (const int*)  d_in[0];
    const float* pos  = (const float*)d_in[1];
    const float* cell = (const float*)d_in[2];
    const float* coff = (const float*)d_in[3];
    const int*   nbr  = (const int*)  d_in[4];
    const float* mask = (const float*)d_in[5];
    const float* emb  = (const float*)d_in[6];
    const float* fw1  = (const float*)d_in[7];
    const float* fb1  = (const float*)d_in[8];
    const float* fw2  = (const float*)d_in[9];
    const float* fb2  = (const float*)d_in[10];
    const float* in2f = (const float*)d_in[11];
    const float* f2w  = (const float*)d_in[12];
    const float* f2b  = (const float*)d_in[13];
    const float* dw   = (const float*)d_in[14];
    const float* db   = (const float*)d_in[15];

    float* x = (float*)d_out;                      // x lives in d_out
    unsigned* codes = (unsigned*)d_ws;             // B*A*N u32         (2 MB)
    __half* Tb = (__half*)(codes + BB*AA*NN);      // 3*KT*FF half      (1.5 MB)
    __half* yA = Tb + 3*KT*FF;                     // B*A*F half        (2 MB)
    __half* yB = yA + BB*AA*FF;                    // B*A*F half        (2 MB)
    short*  Wp = (short*)(yB + BB*AA*FF);          // 12*16384 bf16     (384 KB)

    k_prolog<<<2048 + 12*16384/256, 256, 0, stream>>>(pos, cell, coff, nbr, mask, codes,
                                                      f2w, dw, in2f, fw2, Wp);
    k_tf    <<<384 + BB*AA/16, 512, 0, stream>>>(fw1, fb1, fb2, Wp, Tb, zat, emb, x, yA);

    k_layerM<<<BB*AA/16, 512, 0, stream>>>(codes, Tb,           yA,
                                           Wp + 0*16384, f2b,        Wp + 3*16384, db,
                                           Wp + 7*16384, x, yB);
    k_layerM<<<BB*AA/16, 512, 0, stream>>>(codes, Tb + KT*FF,   yB,
                                           Wp + 1*16384, f2b + FF,   Wp + 4*16384, db + FF,
                                           Wp + 8*16384, x, yA);
    k_layerM<<<BB*AA/16, 512, 0, stream>>>(codes, Tb + 2*KT*FF, yA,
                                           Wp + 2*16384, f2b + 2*FF, Wp + 5*16384, db + 2*FF,
                                           nullptr, x, nullptr);
}